// Round 1
// baseline (1389.890 us; speedup 1.0000x reference)
//
#include <hip/hip_runtime.h>
#include <cstdint>
#include <cstddef>

#define B_SZ 2
#define D_SZ 2048
#define L_SZ 2048
#define R_SZ 128
#define N_SZ 16
#define E_SZ (R_SZ + 2*N_SZ)   // 160

// ---------------------------------------------------------------------------
// K1: causal depthwise conv1d (K=4) + bias + SiLU, with LDS transpose.
// in : h [B, D, L]   out: u [B, L, D]
// ---------------------------------------------------------------------------
__global__ __launch_bounds__(256) void k1_conv(const float* __restrict__ h,
                                               const float* __restrict__ cw,
                                               const float* __restrict__ cb,
                                               float* __restrict__ u) {
  __shared__ __attribute__((aligned(16))) float tile[64 * 69]; // stride 69: conflict-free transposed read
  __shared__ float wsm[64 * 4];
  __shared__ float bsm[64];
  const int b = blockIdx.z, d0 = blockIdx.y * 64, l0 = blockIdx.x * 64;
  const int tid = threadIdx.x;
  if (tid < 64) {
    bsm[tid] = cb[d0 + tid];
#pragma unroll
    for (int k = 0; k < 4; k++) wsm[tid * 4 + k] = cw[(d0 + tid) * 4 + k];
  }
  const float* hb = h + ((size_t)b * D_SZ + d0) * L_SZ;
  // need cols l0-3 .. l0+63 (67 values); pad row to 68 for the strided loop
  for (int i = tid; i < 64 * 68; i += 256) {
    int r = i / 68, c = i - r * 68;
    int gl = l0 - 3 + c;
    float v = 0.f;
    if (c < 67 && gl >= 0) v = hb[(size_t)r * L_SZ + gl];
    tile[r * 69 + c] = v;
  }
  __syncthreads();
  float* ub = u + ((size_t)b * L_SZ + l0) * D_SZ + d0;
  for (int i = tid; i < 64 * 64; i += 256) {
    int ll = i >> 6, dd = i & 63;
    float s = bsm[dd];
#pragma unroll
    for (int k = 0; k < 4; k++) s = fmaf(wsm[dd * 4 + k], tile[dd * 69 + ll + k], s);
    float sv = s / (1.f + __expf(-s));           // silu
    ub[(size_t)ll * D_SZ + dd] = sv;             // coalesced over dd
  }
}

// ---------------------------------------------------------------------------
// K2: ssm[bl][e] = sum_d u[bl][d] * xw[e][d]   (M=4096, E=160, K=2048)
// tile 32 rows x 80 cols, BK=64. thread: 2 rows x 5 cols.
// ---------------------------------------------------------------------------
__global__ __launch_bounds__(256) void k2_gemm1(const float* __restrict__ u,
                                                const float* __restrict__ xw,
                                                float* __restrict__ ssm) {
  __shared__ __attribute__((aligned(16))) float aS[32 * 68]; // 272B row stride: b128-aligned
  __shared__ __attribute__((aligned(16))) float bS[80 * 68];
  const int bl0 = blockIdx.x * 32, e0 = blockIdx.y * 80;
  const int tid = threadIdx.x;
  const int r2 = tid >> 4, c4 = tid & 15;
  float acc[2][5] = {};
  for (int k0 = 0; k0 < D_SZ; k0 += 64) {
    for (int i = tid; i < 32 * 16; i += 256) {   // float4 staging
      int r = i >> 4, c = (i & 15) << 2;
      *(float4*)&aS[r * 68 + c] = *(const float4*)&u[(size_t)(bl0 + r) * D_SZ + k0 + c];
    }
    for (int i = tid; i < 80 * 16; i += 256) {
      int r = i >> 4, c = (i & 15) << 2;
      *(float4*)&bS[r * 68 + c] = *(const float4*)&xw[(size_t)(e0 + r) * D_SZ + k0 + c];
    }
    __syncthreads();
#pragma unroll 2
    for (int k = 0; k < 64; k += 4) {
      float4 a0 = *(float4*)&aS[(r2 * 2 + 0) * 68 + k];
      float4 a1 = *(float4*)&aS[(r2 * 2 + 1) * 68 + k];
#pragma unroll
      for (int j = 0; j < 5; ++j) {
        float4 bv = *(float4*)&bS[(c4 * 5 + j) * 68 + k];
        acc[0][j] = fmaf(a0.x, bv.x, acc[0][j]);
        acc[0][j] = fmaf(a0.y, bv.y, acc[0][j]);
        acc[0][j] = fmaf(a0.z, bv.z, acc[0][j]);
        acc[0][j] = fmaf(a0.w, bv.w, acc[0][j]);
        acc[1][j] = fmaf(a1.x, bv.x, acc[1][j]);
        acc[1][j] = fmaf(a1.y, bv.y, acc[1][j]);
        acc[1][j] = fmaf(a1.z, bv.z, acc[1][j]);
        acc[1][j] = fmaf(a1.w, bv.w, acc[1][j]);
      }
    }
    __syncthreads();
  }
#pragma unroll
  for (int i = 0; i < 2; ++i) {
    size_t row = bl0 + r2 * 2 + i;
#pragma unroll
    for (int j = 0; j < 5; ++j)
      ssm[row * E_SZ + e0 + c4 * 5 + j] = acc[i][j];
  }
}

// ---------------------------------------------------------------------------
// K3: in-place RMSNorm of ssm rows: [0,128) w/ dt_ln_w, [128,144) B_ln_w, [144,160) C_ln_w
// one wave per row.
// ---------------------------------------------------------------------------
__global__ __launch_bounds__(256) void k3_rms(float* __restrict__ ssm,
                                              const float* __restrict__ dtln,
                                              const float* __restrict__ bln,
                                              const float* __restrict__ cln) {
  const int lane = threadIdx.x & 63;
  const int wv = threadIdx.x >> 6;
  const size_t row = (size_t)blockIdx.x * 4 + wv;
  float* p = ssm + row * E_SZ;
  float v0 = p[lane];
  float v1 = p[64 + lane];
  float v2 = (lane < 32) ? p[128 + lane] : 0.f;
  float sdt = v0 * v0 + v1 * v1;
#pragma unroll
  for (int m = 1; m < 64; m <<= 1) sdt += __shfl_xor(sdt, m);
  float sv2 = v2 * v2;
#pragma unroll
  for (int m = 1; m < 16; m <<= 1) sv2 += __shfl_xor(sv2, m); // 16-lane group sums
  float sB = __shfl(sv2, 0);
  float sC = __shfl(sv2, 16);
  float rdt = rsqrtf(sdt * (1.f / 128.f) + 1e-6f);
  float rB  = rsqrtf(sB  * (1.f / 16.f)  + 1e-6f);
  float rC  = rsqrtf(sC  * (1.f / 16.f)  + 1e-6f);
  p[lane]      = v0 * rdt * dtln[lane];
  p[64 + lane] = v1 * rdt * dtln[64 + lane];
  if (lane < 16)      p[128 + lane] = v2 * rB * bln[lane];
  else if (lane < 32) p[128 + lane] = v2 * rC * cln[lane - 16];
}

// ---------------------------------------------------------------------------
// K4: delta[bl][d] = softplus( sum_r dt[bl][r]*dtw[d][r] + dtb[d] )
// M=4096, N=2048, K=128. tile 64x64, thread 4 rows x 4 strided cols (c4+16j).
// ---------------------------------------------------------------------------
__global__ __launch_bounds__(256) void k4_gemm2(const float* __restrict__ ssm,
                                                const float* __restrict__ dtw,
                                                const float* __restrict__ dtb,
                                                float* __restrict__ delta) {
  __shared__ __attribute__((aligned(16))) float aS[64 * 68];
  __shared__ __attribute__((aligned(16))) float bS[64 * 68];
  const int bl0 = blockIdx.x * 64, d0 = blockIdx.y * 64;
  const int tid = threadIdx.x;
  const int r4 = tid >> 4, c4 = tid & 15;
  float acc[4][4] = {};
  for (int k0 = 0; k0 < R_SZ; k0 += 64) {
    for (int i = tid; i < 64 * 16; i += 256) {
      int r = i >> 4, c = (i & 15) << 2;
      *(float4*)&aS[r * 68 + c] = *(const float4*)&ssm[(size_t)(bl0 + r) * E_SZ + k0 + c];
    }
    for (int i = tid; i < 64 * 16; i += 256) {
      int r = i >> 4, c = (i & 15) << 2;
      *(float4*)&bS[r * 68 + c] = *(const float4*)&dtw[(size_t)(d0 + r) * R_SZ + k0 + c];
    }
    __syncthreads();
#pragma unroll 4
    for (int k = 0; k < 64; k += 4) {
      float4 av[4], bv[4];
#pragma unroll
      for (int i = 0; i < 4; i++) av[i] = *(float4*)&aS[(r4 * 4 + i) * 68 + k];
#pragma unroll
      for (int j = 0; j < 4; j++) bv[j] = *(float4*)&bS[(c4 + 16 * j) * 68 + k];
#pragma unroll
      for (int i = 0; i < 4; i++)
#pragma unroll
        for (int j = 0; j < 4; j++) {
          acc[i][j] = fmaf(av[i].x, bv[j].x, acc[i][j]);
          acc[i][j] = fmaf(av[i].y, bv[j].y, acc[i][j]);
          acc[i][j] = fmaf(av[i].z, bv[j].z, acc[i][j]);
          acc[i][j] = fmaf(av[i].w, bv[j].w, acc[i][j]);
        }
    }
    __syncthreads();
  }
#pragma unroll
  for (int i = 0; i < 4; i++) {
    size_t row = bl0 + r4 * 4 + i;
#pragma unroll
    for (int j = 0; j < 4; j++) {
      int d = d0 + c4 + 16 * j;
      float x = acc[i][j] + dtb[d];
      float sp = (x > 20.f) ? x : log1pf(__expf(x));
      delta[row * D_SZ + d] = sp;
    }
  }
}

// ---------------------------------------------------------------------------
// K5: selective scan + skip + gate. thread = (b, d, n); state in register.
// y = sum_n s*C via 16-lane shfl_xor; out = (y + u*Dp) * silu(gate[b,d,l]).
// ---------------------------------------------------------------------------
__global__ __launch_bounds__(256) void k5_scan(const float* __restrict__ u,
                                               const float* __restrict__ delta,
                                               const float* __restrict__ ssm,
                                               const float* __restrict__ gate,
                                               const float* __restrict__ alog,
                                               const float* __restrict__ dparam,
                                               float* __restrict__ out) {
  const int n = threadIdx.x & 15;
  const int dd = threadIdx.x >> 4;        // 0..15
  const int d = blockIdx.x * 16 + dd;
  const int b = blockIdx.y;
  const float a = -__expf(alog[d * N_SZ + n]);
  const float dpv = dparam[d];
  const float* up = u     + ((size_t)b * L_SZ) * D_SZ + d;
  const float* dp = delta + ((size_t)b * L_SZ) * D_SZ + d;
  const float* gp = gate  + ((size_t)b * D_SZ + d) * L_SZ;
  const float* sp = ssm   + ((size_t)b * L_SZ) * E_SZ + R_SZ;
  float* op = out + ((size_t)b * L_SZ) * D_SZ + d;
  float s = 0.f;
  // software-pipelined loads (1 step ahead)
  float ut = up[0], dt = dp[0], Bv = sp[n], Cv = sp[N_SZ + n];
  for (int l = 0; l < L_SZ; ++l) {
    float ut_n = 0.f, dt_n = 0.f, Bv_n = 0.f, Cv_n = 0.f;
    if (l + 1 < L_SZ) {
      size_t o = (size_t)(l + 1);
      ut_n = up[o * D_SZ];
      dt_n = dp[o * D_SZ];
      Bv_n = sp[o * E_SZ + n];
      Cv_n = sp[o * E_SZ + N_SZ + n];
    }
    float dA = __expf(dt * a);
    s = fmaf(dA, s, dt * ut * Bv);
    float part = s * Cv;
    part += __shfl_xor(part, 1);
    part += __shfl_xor(part, 2);
    part += __shfl_xor(part, 4);
    part += __shfl_xor(part, 8);
    if (n == 0) {
      float gv = gp[l];
      float sg = gv / (1.f + __expf(-gv));
      op[(size_t)l * D_SZ] = fmaf(ut, dpv, part) * sg;
    }
    ut = ut_n; dt = dt_n; Bv = Bv_n; Cv = Cv_n;
  }
}

// ---------------------------------------------------------------------------
extern "C" void kernel_launch(void* const* d_in, const int* in_sizes, int n_in,
                              void* d_out, int out_size, void* d_ws, size_t ws_size,
                              hipStream_t stream) {
  const float* h    = (const float*)d_in[0];
  const float* gate = (const float*)d_in[1];
  const float* cw   = (const float*)d_in[2];
  const float* cb   = (const float*)d_in[3];
  const float* xw   = (const float*)d_in[4];
  const float* dtw  = (const float*)d_in[5];
  const float* dtb  = (const float*)d_in[6];
  const float* alog = (const float*)d_in[7];
  const float* dpar = (const float*)d_in[8];
  const float* dtln = (const float*)d_in[9];
  const float* bln  = (const float*)d_in[10];
  const float* cln  = (const float*)d_in[11];
  float* out = (float*)d_out;

  float* u     = (float*)d_ws;                           // B*L*D
  float* delta = u + (size_t)B_SZ * L_SZ * D_SZ;         // B*L*D
  float* ssm   = delta + (size_t)B_SZ * L_SZ * D_SZ;     // B*L*160

  hipLaunchKernelGGL(k1_conv, dim3(L_SZ / 64, D_SZ / 64, B_SZ), dim3(256), 0, stream,
                     h, cw, cb, u);
  hipLaunchKernelGGL(k2_gemm1, dim3((B_SZ * L_SZ) / 32, 2), dim3(256), 0, stream,
                     u, xw, ssm);
  hipLaunchKernelGGL(k3_rms, dim3((B_SZ * L_SZ) / 4), dim3(256), 0, stream,
                     ssm, dtln, bln, cln);
  hipLaunchKernelGGL(k4_gemm2, dim3((B_SZ * L_SZ) / 64, D_SZ / 64), dim3(256), 0, stream,
                     ssm, dtw, dtb, delta);
  hipLaunchKernelGGL(k5_scan, dim3(D_SZ / 16, B_SZ), dim3(256), 0, stream,
                     u, delta, ssm, gate, alog, dpar, out);
}

// Round 2
// 468.999 us; speedup vs baseline: 2.9635x; 2.9635x over previous
//
#include <hip/hip_runtime.h>
#include <cstdint>
#include <cstddef>

#define B_SZ 2
#define D_SZ 2048
#define L_SZ 2048
#define R_SZ 128
#define N_SZ 16
#define E_SZ (R_SZ + 2*N_SZ)   // 160
#define CHN 64                 // chunks over L
#define CLEN 32                // L_SZ / CHN

// ---------------------------------------------------------------------------
// K1: causal depthwise conv1d (K=4) + bias + SiLU, with LDS transpose.
// in : h [B, D, L]   out: u [B, L, D]
// ---------------------------------------------------------------------------
__global__ __launch_bounds__(256) void k1_conv(const float* __restrict__ h,
                                               const float* __restrict__ cw,
                                               const float* __restrict__ cb,
                                               float* __restrict__ u) {
  __shared__ __attribute__((aligned(16))) float tile[64 * 69];
  __shared__ float wsm[64 * 4];
  __shared__ float bsm[64];
  const int b = blockIdx.z, d0 = blockIdx.y * 64, l0 = blockIdx.x * 64;
  const int tid = threadIdx.x;
  if (tid < 64) {
    bsm[tid] = cb[d0 + tid];
#pragma unroll
    for (int k = 0; k < 4; k++) wsm[tid * 4 + k] = cw[(d0 + tid) * 4 + k];
  }
  const float* hb = h + ((size_t)b * D_SZ + d0) * L_SZ;
  for (int i = tid; i < 64 * 68; i += 256) {
    int r = i / 68, c = i - r * 68;
    int gl = l0 - 3 + c;
    float v = 0.f;
    if (c < 67 && gl >= 0) v = hb[(size_t)r * L_SZ + gl];
    tile[r * 69 + c] = v;
  }
  __syncthreads();
  float* ub = u + ((size_t)b * L_SZ + l0) * D_SZ + d0;
  for (int i = tid; i < 64 * 64; i += 256) {
    int ll = i >> 6, dd = i & 63;
    float s = bsm[dd];
#pragma unroll
    for (int k = 0; k < 4; k++) s = fmaf(wsm[dd * 4 + k], tile[dd * 69 + ll + k], s);
    float sv = s / (1.f + __expf(-s));
    ub[(size_t)ll * D_SZ + dd] = sv;
  }
}

// ---------------------------------------------------------------------------
// K2: ssm[bl][e] = sum_d u[bl][d] * xw[e][d]   (M=4096, E=160, K=2048)
// ---------------------------------------------------------------------------
__global__ __launch_bounds__(256) void k2_gemm1(const float* __restrict__ u,
                                                const float* __restrict__ xw,
                                                float* __restrict__ ssm) {
  __shared__ __attribute__((aligned(16))) float aS[32 * 68];
  __shared__ __attribute__((aligned(16))) float bS[80 * 68];
  const int bl0 = blockIdx.x * 32, e0 = blockIdx.y * 80;
  const int tid = threadIdx.x;
  const int r2 = tid >> 4, c4 = tid & 15;
  float acc[2][5] = {};
  for (int k0 = 0; k0 < D_SZ; k0 += 64) {
    for (int i = tid; i < 32 * 16; i += 256) {
      int r = i >> 4, c = (i & 15) << 2;
      *(float4*)&aS[r * 68 + c] = *(const float4*)&u[(size_t)(bl0 + r) * D_SZ + k0 + c];
    }
    for (int i = tid; i < 80 * 16; i += 256) {
      int r = i >> 4, c = (i & 15) << 2;
      *(float4*)&bS[r * 68 + c] = *(const float4*)&xw[(size_t)(e0 + r) * D_SZ + k0 + c];
    }
    __syncthreads();
#pragma unroll 2
    for (int k = 0; k < 64; k += 4) {
      float4 a0 = *(float4*)&aS[(r2 * 2 + 0) * 68 + k];
      float4 a1 = *(float4*)&aS[(r2 * 2 + 1) * 68 + k];
#pragma unroll
      for (int j = 0; j < 5; ++j) {
        float4 bv = *(float4*)&bS[(c4 * 5 + j) * 68 + k];
        acc[0][j] = fmaf(a0.x, bv.x, acc[0][j]);
        acc[0][j] = fmaf(a0.y, bv.y, acc[0][j]);
        acc[0][j] = fmaf(a0.z, bv.z, acc[0][j]);
        acc[0][j] = fmaf(a0.w, bv.w, acc[0][j]);
        acc[1][j] = fmaf(a1.x, bv.x, acc[1][j]);
        acc[1][j] = fmaf(a1.y, bv.y, acc[1][j]);
        acc[1][j] = fmaf(a1.z, bv.z, acc[1][j]);
        acc[1][j] = fmaf(a1.w, bv.w, acc[1][j]);
      }
    }
    __syncthreads();
  }
#pragma unroll
  for (int i = 0; i < 2; ++i) {
    size_t row = bl0 + r2 * 2 + i;
#pragma unroll
    for (int j = 0; j < 5; ++j)
      ssm[row * E_SZ + e0 + c4 * 5 + j] = acc[i][j];
  }
}

// ---------------------------------------------------------------------------
// K3: in-place RMSNorm of ssm rows. one wave per row.
// ---------------------------------------------------------------------------
__global__ __launch_bounds__(256) void k3_rms(float* __restrict__ ssm,
                                              const float* __restrict__ dtln,
                                              const float* __restrict__ bln,
                                              const float* __restrict__ cln) {
  const int lane = threadIdx.x & 63;
  const int wv = threadIdx.x >> 6;
  const size_t row = (size_t)blockIdx.x * 4 + wv;
  float* p = ssm + row * E_SZ;
  float v0 = p[lane];
  float v1 = p[64 + lane];
  float v2 = (lane < 32) ? p[128 + lane] : 0.f;
  float sdt = v0 * v0 + v1 * v1;
#pragma unroll
  for (int m = 1; m < 64; m <<= 1) sdt += __shfl_xor(sdt, m);
  float sv2 = v2 * v2;
#pragma unroll
  for (int m = 1; m < 16; m <<= 1) sv2 += __shfl_xor(sv2, m);
  float sB = __shfl(sv2, 0);
  float sC = __shfl(sv2, 16);
  float rdt = rsqrtf(sdt * (1.f / 128.f) + 1e-6f);
  float rB  = rsqrtf(sB  * (1.f / 16.f)  + 1e-6f);
  float rC  = rsqrtf(sC  * (1.f / 16.f)  + 1e-6f);
  p[lane]      = v0 * rdt * dtln[lane];
  p[64 + lane] = v1 * rdt * dtln[64 + lane];
  if (lane < 16)      p[128 + lane] = v2 * rB * bln[lane];
  else if (lane < 32) p[128 + lane] = v2 * rC * cln[lane - 16];
}

// ---------------------------------------------------------------------------
// K4: delta[bl][d] = softplus( dt @ dt_w^T + dt_b )  (M=4096, N=2048, K=128)
// ---------------------------------------------------------------------------
__global__ __launch_bounds__(256) void k4_gemm2(const float* __restrict__ ssm,
                                                const float* __restrict__ dtw,
                                                const float* __restrict__ dtb,
                                                float* __restrict__ delta) {
  __shared__ __attribute__((aligned(16))) float aS[64 * 68];
  __shared__ __attribute__((aligned(16))) float bS[64 * 68];
  const int bl0 = blockIdx.x * 64, d0 = blockIdx.y * 64;
  const int tid = threadIdx.x;
  const int r4 = tid >> 4, c4 = tid & 15;
  float acc[4][4] = {};
  for (int k0 = 0; k0 < R_SZ; k0 += 64) {
    for (int i = tid; i < 64 * 16; i += 256) {
      int r = i >> 4, c = (i & 15) << 2;
      *(float4*)&aS[r * 68 + c] = *(const float4*)&ssm[(size_t)(bl0 + r) * E_SZ + k0 + c];
    }
    for (int i = tid; i < 64 * 16; i += 256) {
      int r = i >> 4, c = (i & 15) << 2;
      *(float4*)&bS[r * 68 + c] = *(const float4*)&dtw[(size_t)(d0 + r) * R_SZ + k0 + c];
    }
    __syncthreads();
#pragma unroll 4
    for (int k = 0; k < 64; k += 4) {
      float4 av[4], bv[4];
#pragma unroll
      for (int i = 0; i < 4; i++) av[i] = *(float4*)&aS[(r4 * 4 + i) * 68 + k];
#pragma unroll
      for (int j = 0; j < 4; j++) bv[j] = *(float4*)&bS[(c4 + 16 * j) * 68 + k];
#pragma unroll
      for (int i = 0; i < 4; i++)
#pragma unroll
        for (int j = 0; j < 4; j++) {
          acc[i][j] = fmaf(av[i].x, bv[j].x, acc[i][j]);
          acc[i][j] = fmaf(av[i].y, bv[j].y, acc[i][j]);
          acc[i][j] = fmaf(av[i].z, bv[j].z, acc[i][j]);
          acc[i][j] = fmaf(av[i].w, bv[j].w, acc[i][j]);
        }
    }
    __syncthreads();
  }
#pragma unroll
  for (int i = 0; i < 4; i++) {
    size_t row = bl0 + r4 * 4 + i;
#pragma unroll
    for (int j = 0; j < 4; j++) {
      int d = d0 + c4 + 16 * j;
      float x = acc[i][j] + dtb[d];
      float sp = (x > 20.f) ? x : log1pf(__expf(x));
      delta[row * D_SZ + d] = sp;
    }
  }
}

// ---------------------------------------------------------------------------
// K5a: chunked scan, phase A. thread = (b, d, chunk), N=16 states in regs.
// Writes local chunk-final state (init=0) to chk[b][c][d][n] and sum(dt) to
// sumdt[b][c][d].
// ---------------------------------------------------------------------------
__global__ __launch_bounds__(256) void k5a(const float* __restrict__ u,
                                           const float* __restrict__ delta,
                                           const float* __restrict__ ssm,
                                           const float* __restrict__ alog,
                                           float* __restrict__ chk,
                                           float* __restrict__ sumdt) {
  const int d = blockIdx.x * 256 + threadIdx.x;
  const int c = blockIdx.y, b = blockIdx.z;
  float a[N_SZ], s[N_SZ];
#pragma unroll
  for (int i = 0; i < 4; i++) {
    float4 al = *(const float4*)&alog[(size_t)d * N_SZ + 4 * i];
    a[4 * i + 0] = -__expf(al.x); a[4 * i + 1] = -__expf(al.y);
    a[4 * i + 2] = -__expf(al.z); a[4 * i + 3] = -__expf(al.w);
  }
#pragma unroll
  for (int n = 0; n < N_SZ; n++) s[n] = 0.f;
  const size_t l0 = (size_t)c * CLEN;
  const float* dp = delta + ((size_t)b * L_SZ + l0) * D_SZ + d;
  const float* up = u     + ((size_t)b * L_SZ + l0) * D_SZ + d;
  const float* bp = ssm   + ((size_t)b * L_SZ + l0) * E_SZ + R_SZ;
  float sdt = 0.f;
  for (int t = 0; t < CLEN; ++t) {
    float dt = dp[(size_t)t * D_SZ];
    float ut = up[(size_t)t * D_SZ];
    float Bv[N_SZ];
#pragma unroll
    for (int i = 0; i < 4; i++) {
      float4 bb = *(const float4*)&bp[(size_t)t * E_SZ + 4 * i];
      Bv[4 * i] = bb.x; Bv[4 * i + 1] = bb.y; Bv[4 * i + 2] = bb.z; Bv[4 * i + 3] = bb.w;
    }
    float du = dt * ut;
    sdt += dt;
#pragma unroll
    for (int n = 0; n < N_SZ; n++)
      s[n] = fmaf(__expf(a[n] * dt), s[n], du * Bv[n]);
  }
  float* cp = chk + (((size_t)b * CHN + c) * D_SZ + d) * N_SZ;
#pragma unroll
  for (int i = 0; i < 4; i++)
    *(float4*)&cp[4 * i] = make_float4(s[4 * i], s[4 * i + 1], s[4 * i + 2], s[4 * i + 3]);
  sumdt[((size_t)b * CHN + c) * D_SZ + d] = sdt;
}

// ---------------------------------------------------------------------------
// K5b: prefix over chunk summaries, in place. thread = (b, d, n).
// After this, chk[b][c][d][n] holds the state at the START of chunk c.
// ---------------------------------------------------------------------------
__global__ __launch_bounds__(256) void k5b(const float* __restrict__ alog,
                                           const float* __restrict__ sumdt,
                                           float* __restrict__ chk) {
  const int g = blockIdx.x * 256 + threadIdx.x;      // over B*D*16 = 65536
  const int n = g & 15;
  const int d = (g >> 4) & (D_SZ - 1);
  const int b = g >> 15;
  const float a = -__expf(alog[(size_t)d * N_SZ + n]);
  float s = 0.f;
  for (int c = 0; c < CHN; ++c) {
    const size_t idx = (((size_t)b * CHN + c) * D_SZ + d) * N_SZ + n;
    float v = chk[idx];
    float sdt = sumdt[((size_t)b * CHN + c) * D_SZ + d];
    float init = s;
    s = fmaf(__expf(a * sdt), s, v);
    chk[idx] = init;
  }
}

// ---------------------------------------------------------------------------
// K5c: chunked scan, phase C. Re-run each chunk from its init state; fused
// y = s·C, skip u*Dp, and gate multiply. thread = (b, d, chunk).
// ---------------------------------------------------------------------------
__global__ __launch_bounds__(256) void k5c(const float* __restrict__ u,
                                           const float* __restrict__ delta,
                                           const float* __restrict__ ssm,
                                           const float* __restrict__ gate,
                                           const float* __restrict__ alog,
                                           const float* __restrict__ dparam,
                                           const float* __restrict__ chk,
                                           float* __restrict__ out) {
  const int d = blockIdx.x * 256 + threadIdx.x;
  const int c = blockIdx.y, b = blockIdx.z;
  float a[N_SZ], s[N_SZ];
#pragma unroll
  for (int i = 0; i < 4; i++) {
    float4 al = *(const float4*)&alog[(size_t)d * N_SZ + 4 * i];
    a[4 * i + 0] = -__expf(al.x); a[4 * i + 1] = -__expf(al.y);
    a[4 * i + 2] = -__expf(al.z); a[4 * i + 3] = -__expf(al.w);
  }
  const float* cp = chk + (((size_t)b * CHN + c) * D_SZ + d) * N_SZ;
#pragma unroll
  for (int i = 0; i < 4; i++) {
    float4 sv = *(const float4*)&cp[4 * i];
    s[4 * i] = sv.x; s[4 * i + 1] = sv.y; s[4 * i + 2] = sv.z; s[4 * i + 3] = sv.w;
  }
  const float dpv = dparam[d];
  const size_t l0 = (size_t)c * CLEN;
  const float* dp = delta + ((size_t)b * L_SZ + l0) * D_SZ + d;
  const float* up = u     + ((size_t)b * L_SZ + l0) * D_SZ + d;
  const float* bp = ssm   + ((size_t)b * L_SZ + l0) * E_SZ + R_SZ;
  const float* gp = gate  + ((size_t)b * D_SZ + d) * L_SZ + l0;
  float* op = out + ((size_t)b * L_SZ + l0) * D_SZ + d;
  for (int t = 0; t < CLEN; ++t) {
    float dt = dp[(size_t)t * D_SZ];
    float ut = up[(size_t)t * D_SZ];
    float Bv[N_SZ], Cv[N_SZ];
#pragma unroll
    for (int i = 0; i < 4; i++) {
      float4 bb = *(const float4*)&bp[(size_t)t * E_SZ + 4 * i];
      Bv[4 * i] = bb.x; Bv[4 * i + 1] = bb.y; Bv[4 * i + 2] = bb.z; Bv[4 * i + 3] = bb.w;
      float4 cc = *(const float4*)&bp[(size_t)t * E_SZ + N_SZ + 4 * i];
      Cv[4 * i] = cc.x; Cv[4 * i + 1] = cc.y; Cv[4 * i + 2] = cc.z; Cv[4 * i + 3] = cc.w;
    }
    float du = dt * ut;
    float y = 0.f;
#pragma unroll
    for (int n = 0; n < N_SZ; n++) {
      s[n] = fmaf(__expf(a[n] * dt), s[n], du * Bv[n]);
      y = fmaf(s[n], Cv[n], y);
    }
    float gv = gp[t];
    float sg = gv / (1.f + __expf(-gv));
    op[(size_t)t * D_SZ] = fmaf(ut, dpv, y) * sg;
  }
}

// ---------------------------------------------------------------------------
extern "C" void kernel_launch(void* const* d_in, const int* in_sizes, int n_in,
                              void* d_out, int out_size, void* d_ws, size_t ws_size,
                              hipStream_t stream) {
  const float* h    = (const float*)d_in[0];
  const float* gate = (const float*)d_in[1];
  const float* cw   = (const float*)d_in[2];
  const float* cb   = (const float*)d_in[3];
  const float* xw   = (const float*)d_in[4];
  const float* dtw  = (const float*)d_in[5];
  const float* dtb  = (const float*)d_in[6];
  const float* alog = (const float*)d_in[7];
  const float* dpar = (const float*)d_in[8];
  const float* dtln = (const float*)d_in[9];
  const float* bln  = (const float*)d_in[10];
  const float* cln  = (const float*)d_in[11];
  float* out = (float*)d_out;

  float* u     = (float*)d_ws;                               // B*L*D
  float* delta = u + (size_t)B_SZ * L_SZ * D_SZ;             // B*L*D
  float* ssm   = delta + (size_t)B_SZ * L_SZ * D_SZ;         // B*L*E
  float* chk   = ssm + (size_t)B_SZ * L_SZ * E_SZ;           // B*CHN*D*N
  float* sumdt = chk + (size_t)B_SZ * CHN * D_SZ * N_SZ;     // B*CHN*D

  hipLaunchKernelGGL(k1_conv, dim3(L_SZ / 64, D_SZ / 64, B_SZ), dim3(256), 0, stream,
                     h, cw, cb, u);
  hipLaunchKernelGGL(k2_gemm1, dim3((B_SZ * L_SZ) / 32, 2), dim3(256), 0, stream,
                     u, xw, ssm);
  hipLaunchKernelGGL(k3_rms, dim3((B_SZ * L_SZ) / 4), dim3(256), 0, stream,
                     ssm, dtln, bln, cln);
  hipLaunchKernelGGL(k4_gemm2, dim3((B_SZ * L_SZ) / 64, D_SZ / 64), dim3(256), 0, stream,
                     ssm, dtw, dtb, delta);
  hipLaunchKernelGGL(k5a, dim3(D_SZ / 256, CHN, B_SZ), dim3(256), 0, stream,
                     u, delta, ssm, alog, chk, sumdt);
  hipLaunchKernelGGL(k5b, dim3((B_SZ * D_SZ * N_SZ) / 256), dim3(256), 0, stream,
                     alog, sumdt, chk);
  hipLaunchKernelGGL(k5c, dim3(D_SZ / 256, CHN, B_SZ), dim3(256), 0, stream,
                     u, delta, ssm, gate, alog, dpar, chk, out);
}

// Round 3
// 374.307 us; speedup vs baseline: 3.7132x; 1.2530x over previous
//
#include <hip/hip_runtime.h>
#include <cstdint>
#include <cstddef>

#define B_SZ 2
#define D_SZ 2048
#define L_SZ 2048
#define R_SZ 128
#define N_SZ 16
#define E_SZ (R_SZ + 2*N_SZ)   // 160
#define CHN 64                 // chunks over L
#define CLEN 32                // L_SZ / CHN
#define KS 8                   // split-K factor for GEMM1
#define MROWS (B_SZ * L_SZ)    // 4096

// ---------------------------------------------------------------------------
// K1: causal depthwise conv1d (K=4) + bias + SiLU, with LDS transpose.
// in : h [B, D, L]   out: u [B, L, D]
// ---------------------------------------------------------------------------
__global__ __launch_bounds__(256) void k1_conv(const float* __restrict__ h,
                                               const float* __restrict__ cw,
                                               const float* __restrict__ cb,
                                               float* __restrict__ u) {
  __shared__ __attribute__((aligned(16))) float tile[64 * 69];
  __shared__ float wsm[64 * 4];
  __shared__ float bsm[64];
  const int b = blockIdx.z, d0 = blockIdx.y * 64, l0 = blockIdx.x * 64;
  const int tid = threadIdx.x;
  if (tid < 64) {
    bsm[tid] = cb[d0 + tid];
#pragma unroll
    for (int k = 0; k < 4; k++) wsm[tid * 4 + k] = cw[(d0 + tid) * 4 + k];
  }
  const float* hb = h + ((size_t)b * D_SZ + d0) * L_SZ;
  for (int i = tid; i < 64 * 68; i += 256) {
    int r = i / 68, c = i - r * 68;
    int gl = l0 - 3 + c;
    float v = 0.f;
    if (c < 67 && gl >= 0) v = hb[(size_t)r * L_SZ + gl];
    tile[r * 69 + c] = v;
  }
  __syncthreads();
  float* ub = u + ((size_t)b * L_SZ + l0) * D_SZ + d0;
  for (int i = tid; i < 64 * 64; i += 256) {
    int ll = i >> 6, dd = i & 63;
    float s = bsm[dd];
#pragma unroll
    for (int k = 0; k < 4; k++) s = fmaf(wsm[dd * 4 + k], tile[dd * 69 + ll + k], s);
    float sv = s / (1.f + __expf(-s));
    ub[(size_t)ll * D_SZ + dd] = sv;
  }
}

// ---------------------------------------------------------------------------
// K2: split-K GEMM1 partials.
// pssm[ks][bl][e] = sum_{d in slice ks} u[bl][d] * xw[e][d]
// M=4096, E=160, Kslice=256. tile 32 rows x 80 cols, BK=64.
// grid (128, 2, 8) = 2048 blocks -> ~5 blocks/CU (LDS-limited).
// ---------------------------------------------------------------------------
__global__ __launch_bounds__(256) void k2_gemm1(const float* __restrict__ u,
                                                const float* __restrict__ xw,
                                                float* __restrict__ pssm) {
  __shared__ __attribute__((aligned(16))) float aS[32 * 68];
  __shared__ __attribute__((aligned(16))) float bS[80 * 68];
  const int bl0 = blockIdx.x * 32, e0 = blockIdx.y * 80;
  const int kbase = blockIdx.z * (D_SZ / KS);
  const int tid = threadIdx.x;
  const int r2 = tid >> 4, c4 = tid & 15;
  float acc[2][5] = {};
  for (int k0 = kbase; k0 < kbase + D_SZ / KS; k0 += 64) {
    for (int i = tid; i < 32 * 16; i += 256) {
      int r = i >> 4, c = (i & 15) << 2;
      *(float4*)&aS[r * 68 + c] = *(const float4*)&u[(size_t)(bl0 + r) * D_SZ + k0 + c];
    }
    for (int i = tid; i < 80 * 16; i += 256) {
      int r = i >> 4, c = (i & 15) << 2;
      *(float4*)&bS[r * 68 + c] = *(const float4*)&xw[(size_t)(e0 + r) * D_SZ + k0 + c];
    }
    __syncthreads();
#pragma unroll 2
    for (int k = 0; k < 64; k += 4) {
      float4 a0 = *(float4*)&aS[(r2 * 2 + 0) * 68 + k];
      float4 a1 = *(float4*)&aS[(r2 * 2 + 1) * 68 + k];
#pragma unroll
      for (int j = 0; j < 5; ++j) {
        float4 bv = *(float4*)&bS[(c4 * 5 + j) * 68 + k];
        acc[0][j] = fmaf(a0.x, bv.x, acc[0][j]);
        acc[0][j] = fmaf(a0.y, bv.y, acc[0][j]);
        acc[0][j] = fmaf(a0.z, bv.z, acc[0][j]);
        acc[0][j] = fmaf(a0.w, bv.w, acc[0][j]);
        acc[1][j] = fmaf(a1.x, bv.x, acc[1][j]);
        acc[1][j] = fmaf(a1.y, bv.y, acc[1][j]);
        acc[1][j] = fmaf(a1.z, bv.z, acc[1][j]);
        acc[1][j] = fmaf(a1.w, bv.w, acc[1][j]);
      }
    }
    __syncthreads();
  }
  float* pb = pssm + (size_t)blockIdx.z * MROWS * E_SZ;
#pragma unroll
  for (int i = 0; i < 2; ++i) {
    size_t row = bl0 + r2 * 2 + i;
#pragma unroll
    for (int j = 0; j < 5; ++j)
      pb[row * E_SZ + e0 + c4 * 5 + j] = acc[i][j];
  }
}

// ---------------------------------------------------------------------------
// K3: reduce KS split-K partials + RMSNorm -> final ssm. one wave per row.
// ---------------------------------------------------------------------------
__global__ __launch_bounds__(256) void k3_rms(const float* __restrict__ pssm,
                                              float* __restrict__ ssm,
                                              const float* __restrict__ dtln,
                                              const float* __restrict__ bln,
                                              const float* __restrict__ cln) {
  const int lane = threadIdx.x & 63;
  const int wv = threadIdx.x >> 6;
  const size_t row = (size_t)blockIdx.x * 4 + wv;
  float v0 = 0.f, v1 = 0.f, v2 = 0.f;
#pragma unroll
  for (int ks = 0; ks < KS; ++ks) {
    const float* q = pssm + ((size_t)ks * MROWS + row) * E_SZ;
    v0 += q[lane];
    v1 += q[64 + lane];
    if (lane < 32) v2 += q[128 + lane];
  }
  float sdt = v0 * v0 + v1 * v1;
#pragma unroll
  for (int m = 1; m < 64; m <<= 1) sdt += __shfl_xor(sdt, m);
  float sv2 = v2 * v2;
#pragma unroll
  for (int m = 1; m < 16; m <<= 1) sv2 += __shfl_xor(sv2, m);
  float sB = __shfl(sv2, 0);
  float sC = __shfl(sv2, 16);
  float rdt = rsqrtf(sdt * (1.f / 128.f) + 1e-6f);
  float rB  = rsqrtf(sB  * (1.f / 16.f)  + 1e-6f);
  float rC  = rsqrtf(sC  * (1.f / 16.f)  + 1e-6f);
  float* p = ssm + row * E_SZ;
  p[lane]      = v0 * rdt * dtln[lane];
  p[64 + lane] = v1 * rdt * dtln[64 + lane];
  if (lane < 16)      p[128 + lane] = v2 * rB * bln[lane];
  else if (lane < 32) p[128 + lane] = v2 * rC * cln[lane - 16];
}

// ---------------------------------------------------------------------------
// K4: delta[bl][d] = softplus( dt @ dt_w^T + dt_b )  (M=4096, N=2048, K=128)
// ---------------------------------------------------------------------------
__global__ __launch_bounds__(256) void k4_gemm2(const float* __restrict__ ssm,
                                                const float* __restrict__ dtw,
                                                const float* __restrict__ dtb,
                                                float* __restrict__ delta) {
  __shared__ __attribute__((aligned(16))) float aS[64 * 68];
  __shared__ __attribute__((aligned(16))) float bS[64 * 68];
  const int bl0 = blockIdx.x * 64, d0 = blockIdx.y * 64;
  const int tid = threadIdx.x;
  const int r4 = tid >> 4, c4 = tid & 15;
  float acc[4][4] = {};
  for (int k0 = 0; k0 < R_SZ; k0 += 64) {
    for (int i = tid; i < 64 * 16; i += 256) {
      int r = i >> 4, c = (i & 15) << 2;
      *(float4*)&aS[r * 68 + c] = *(const float4*)&ssm[(size_t)(bl0 + r) * E_SZ + k0 + c];
    }
    for (int i = tid; i < 64 * 16; i += 256) {
      int r = i >> 4, c = (i & 15) << 2;
      *(float4*)&bS[r * 68 + c] = *(const float4*)&dtw[(size_t)(d0 + r) * R_SZ + k0 + c];
    }
    __syncthreads();
#pragma unroll 4
    for (int k = 0; k < 64; k += 4) {
      float4 av[4], bv[4];
#pragma unroll
      for (int i = 0; i < 4; i++) av[i] = *(float4*)&aS[(r4 * 4 + i) * 68 + k];
#pragma unroll
      for (int j = 0; j < 4; j++) bv[j] = *(float4*)&bS[(c4 + 16 * j) * 68 + k];
#pragma unroll
      for (int i = 0; i < 4; i++)
#pragma unroll
        for (int j = 0; j < 4; j++) {
          acc[i][j] = fmaf(av[i].x, bv[j].x, acc[i][j]);
          acc[i][j] = fmaf(av[i].y, bv[j].y, acc[i][j]);
          acc[i][j] = fmaf(av[i].z, bv[j].z, acc[i][j]);
          acc[i][j] = fmaf(av[i].w, bv[j].w, acc[i][j]);
        }
    }
    __syncthreads();
  }
#pragma unroll
  for (int i = 0; i < 4; i++) {
    size_t row = bl0 + r4 * 4 + i;
#pragma unroll
    for (int j = 0; j < 4; j++) {
      int d = d0 + c4 + 16 * j;
      float x = acc[i][j] + dtb[d];
      float sp = (x > 20.f) ? x : log1pf(__expf(x));
      delta[row * D_SZ + d] = sp;
    }
  }
}

// ---------------------------------------------------------------------------
// K5a: chunked scan, phase A. thread = (b, d, chunk), N=16 states in regs.
// ---------------------------------------------------------------------------
__global__ __launch_bounds__(256) void k5a(const float* __restrict__ u,
                                           const float* __restrict__ delta,
                                           const float* __restrict__ ssm,
                                           const float* __restrict__ alog,
                                           float* __restrict__ chk,
                                           float* __restrict__ sumdt) {
  const int d = blockIdx.x * 256 + threadIdx.x;
  const int c = blockIdx.y, b = blockIdx.z;
  float a[N_SZ], s[N_SZ];
#pragma unroll
  for (int i = 0; i < 4; i++) {
    float4 al = *(const float4*)&alog[(size_t)d * N_SZ + 4 * i];
    a[4 * i + 0] = -__expf(al.x); a[4 * i + 1] = -__expf(al.y);
    a[4 * i + 2] = -__expf(al.z); a[4 * i + 3] = -__expf(al.w);
  }
#pragma unroll
  for (int n = 0; n < N_SZ; n++) s[n] = 0.f;
  const size_t l0 = (size_t)c * CLEN;
  const float* dp = delta + ((size_t)b * L_SZ + l0) * D_SZ + d;
  const float* up = u     + ((size_t)b * L_SZ + l0) * D_SZ + d;
  const float* bp = ssm   + ((size_t)b * L_SZ + l0) * E_SZ + R_SZ;
  float sdt = 0.f;
  for (int t = 0; t < CLEN; ++t) {
    float dt = dp[(size_t)t * D_SZ];
    float ut = up[(size_t)t * D_SZ];
    float Bv[N_SZ];
#pragma unroll
    for (int i = 0; i < 4; i++) {
      float4 bb = *(const float4*)&bp[(size_t)t * E_SZ + 4 * i];
      Bv[4 * i] = bb.x; Bv[4 * i + 1] = bb.y; Bv[4 * i + 2] = bb.z; Bv[4 * i + 3] = bb.w;
    }
    float du = dt * ut;
    sdt += dt;
#pragma unroll
    for (int n = 0; n < N_SZ; n++)
      s[n] = fmaf(__expf(a[n] * dt), s[n], du * Bv[n]);
  }
  float* cp = chk + (((size_t)b * CHN + c) * D_SZ + d) * N_SZ;
#pragma unroll
  for (int i = 0; i < 4; i++)
    *(float4*)&cp[4 * i] = make_float4(s[4 * i], s[4 * i + 1], s[4 * i + 2], s[4 * i + 3]);
  sumdt[((size_t)b * CHN + c) * D_SZ + d] = sdt;
}

// ---------------------------------------------------------------------------
// K5b: prefix over chunk summaries, in place. thread = (b, d, n).
// ---------------------------------------------------------------------------
__global__ __launch_bounds__(256) void k5b(const float* __restrict__ alog,
                                           const float* __restrict__ sumdt,
                                           float* __restrict__ chk) {
  const int g = blockIdx.x * 256 + threadIdx.x;      // over B*D*16 = 65536
  const int n = g & 15;
  const int d = (g >> 4) & (D_SZ - 1);
  const int b = g >> 15;
  const float a = -__expf(alog[(size_t)d * N_SZ + n]);
  float s = 0.f;
  for (int c = 0; c < CHN; ++c) {
    const size_t idx = (((size_t)b * CHN + c) * D_SZ + d) * N_SZ + n;
    float v = chk[idx];
    float sdt = sumdt[((size_t)b * CHN + c) * D_SZ + d];
    float init = s;
    s = fmaf(__expf(a * sdt), s, v);
    chk[idx] = init;
  }
}

// ---------------------------------------------------------------------------
// K5c: chunked scan, phase C. Re-run chunk from init state; fused y, skip, gate.
// ---------------------------------------------------------------------------
__global__ __launch_bounds__(256) void k5c(const float* __restrict__ u,
                                           const float* __restrict__ delta,
                                           const float* __restrict__ ssm,
                                           const float* __restrict__ gate,
                                           const float* __restrict__ alog,
                                           const float* __restrict__ dparam,
                                           const float* __restrict__ chk,
                                           float* __restrict__ out) {
  const int d = blockIdx.x * 256 + threadIdx.x;
  const int c = blockIdx.y, b = blockIdx.z;
  float a[N_SZ], s[N_SZ];
#pragma unroll
  for (int i = 0; i < 4; i++) {
    float4 al = *(const float4*)&alog[(size_t)d * N_SZ + 4 * i];
    a[4 * i + 0] = -__expf(al.x); a[4 * i + 1] = -__expf(al.y);
    a[4 * i + 2] = -__expf(al.z); a[4 * i + 3] = -__expf(al.w);
  }
  const float* cp = chk + (((size_t)b * CHN + c) * D_SZ + d) * N_SZ;
#pragma unroll
  for (int i = 0; i < 4; i++) {
    float4 sv = *(const float4*)&cp[4 * i];
    s[4 * i] = sv.x; s[4 * i + 1] = sv.y; s[4 * i + 2] = sv.z; s[4 * i + 3] = sv.w;
  }
  const float dpv = dparam[d];
  const size_t l0 = (size_t)c * CLEN;
  const float* dp = delta + ((size_t)b * L_SZ + l0) * D_SZ + d;
  const float* up = u     + ((size_t)b * L_SZ + l0) * D_SZ + d;
  const float* bp = ssm   + ((size_t)b * L_SZ + l0) * E_SZ + R_SZ;
  const float* gp = gate  + ((size_t)b * D_SZ + d) * L_SZ + l0;
  float* op = out + ((size_t)b * L_SZ + l0) * D_SZ + d;
  for (int t = 0; t < CLEN; ++t) {
    float dt = dp[(size_t)t * D_SZ];
    float ut = up[(size_t)t * D_SZ];
    float Bv[N_SZ], Cv[N_SZ];
#pragma unroll
    for (int i = 0; i < 4; i++) {
      float4 bb = *(const float4*)&bp[(size_t)t * E_SZ + 4 * i];
      Bv[4 * i] = bb.x; Bv[4 * i + 1] = bb.y; Bv[4 * i + 2] = bb.z; Bv[4 * i + 3] = bb.w;
      float4 cc = *(const float4*)&bp[(size_t)t * E_SZ + N_SZ + 4 * i];
      Cv[4 * i] = cc.x; Cv[4 * i + 1] = cc.y; Cv[4 * i + 2] = cc.z; Cv[4 * i + 3] = cc.w;
    }
    float du = dt * ut;
    float y = 0.f;
#pragma unroll
    for (int n = 0; n < N_SZ; n++) {
      s[n] = fmaf(__expf(a[n] * dt), s[n], du * Bv[n]);
      y = fmaf(s[n], Cv[n], y);
    }
    float gv = gp[t];
    float sg = gv / (1.f + __expf(-gv));
    op[(size_t)t * D_SZ] = fmaf(ut, dpv, y) * sg;
  }
}

// ---------------------------------------------------------------------------
extern "C" void kernel_launch(void* const* d_in, const int* in_sizes, int n_in,
                              void* d_out, int out_size, void* d_ws, size_t ws_size,
                              hipStream_t stream) {
  const float* h    = (const float*)d_in[0];
  const float* gate = (const float*)d_in[1];
  const float* cw   = (const float*)d_in[2];
  const float* cb   = (const float*)d_in[3];
  const float* xw   = (const float*)d_in[4];
  const float* dtw  = (const float*)d_in[5];
  const float* dtb  = (const float*)d_in[6];
  const float* alog = (const float*)d_in[7];
  const float* dpar = (const float*)d_in[8];
  const float* dtln = (const float*)d_in[9];
  const float* bln  = (const float*)d_in[10];
  const float* cln  = (const float*)d_in[11];
  float* out = (float*)d_out;

  float* u     = (float*)d_ws;                               // B*L*D
  float* delta = u + (size_t)B_SZ * L_SZ * D_SZ;             // B*L*D (aliases pssm)
  float* pssm  = delta;                                      // KS*MROWS*E (21MB <= 33.5MB) — dead before k4 writes delta
  float* ssm   = delta + (size_t)B_SZ * L_SZ * D_SZ;         // B*L*E
  float* chk   = ssm + (size_t)B_SZ * L_SZ * E_SZ;           // B*CHN*D*N
  float* sumdt = chk + (size_t)B_SZ * CHN * D_SZ * N_SZ;     // B*CHN*D

  hipLaunchKernelGGL(k1_conv, dim3(L_SZ / 64, D_SZ / 64, B_SZ), dim3(256), 0, stream,
                     h, cw, cb, u);
  hipLaunchKernelGGL(k2_gemm1, dim3(MROWS / 32, 2, KS), dim3(256), 0, stream,
                     u, xw, pssm);
  hipLaunchKernelGGL(k3_rms, dim3(MROWS / 4), dim3(256), 0, stream,
                     pssm, ssm, dtln, bln, cln);
  hipLaunchKernelGGL(k4_gemm2, dim3(MROWS / 64, D_SZ / 64), dim3(256), 0, stream,
                     ssm, dtw, dtb, delta);
  hipLaunchKernelGGL(k5a, dim3(D_SZ / 256, CHN, B_SZ), dim3(256), 0, stream,
                     u, delta, ssm, alog, chk, sumdt);
  hipLaunchKernelGGL(k5b, dim3((B_SZ * D_SZ * N_SZ) / 256), dim3(256), 0, stream,
                     alog, sumdt, chk);
  hipLaunchKernelGGL(k5c, dim3(D_SZ / 256, CHN, B_SZ), dim3(256), 0, stream,
                     u, delta, ssm, gate, alog, dpar, chk, out);
}

// Round 4
// 358.157 us; speedup vs baseline: 3.8807x; 1.0451x over previous
//
#include <hip/hip_runtime.h>
#include <cstdint>
#include <cstddef>

#define B_SZ 2
#define D_SZ 2048
#define L_SZ 2048
#define R_SZ 128
#define N_SZ 16
#define E_SZ (R_SZ + 2*N_SZ)   // 160
#define CHN 128                // chunks over L
#define CLEN 16                // L_SZ / CHN
#define KS 8                   // split-K factor for GEMM1
#define MROWS (B_SZ * L_SZ)    // 4096

// ---------------------------------------------------------------------------
// K1: causal depthwise conv1d (K=4) + bias + SiLU, with LDS transpose.
// in : h [B, D, L]   out: u [B, L, D]
// ---------------------------------------------------------------------------
__global__ __launch_bounds__(256) void k1_conv(const float* __restrict__ h,
                                               const float* __restrict__ cw,
                                               const float* __restrict__ cb,
                                               float* __restrict__ u) {
  __shared__ __attribute__((aligned(16))) float tile[64 * 69];
  __shared__ float wsm[64 * 4];
  __shared__ float bsm[64];
  const int b = blockIdx.z, d0 = blockIdx.y * 64, l0 = blockIdx.x * 64;
  const int tid = threadIdx.x;
  if (tid < 64) {
    bsm[tid] = cb[d0 + tid];
#pragma unroll
    for (int k = 0; k < 4; k++) wsm[tid * 4 + k] = cw[(d0 + tid) * 4 + k];
  }
  const float* hb = h + ((size_t)b * D_SZ + d0) * L_SZ;
  for (int i = tid; i < 64 * 68; i += 256) {
    int r = i / 68, c = i - r * 68;
    int gl = l0 - 3 + c;
    float v = 0.f;
    if (c < 67 && gl >= 0) v = hb[(size_t)r * L_SZ + gl];
    tile[r * 69 + c] = v;
  }
  __syncthreads();
  float* ub = u + ((size_t)b * L_SZ + l0) * D_SZ + d0;
  for (int i = tid; i < 64 * 64; i += 256) {
    int ll = i >> 6, dd = i & 63;
    float s = bsm[dd];
#pragma unroll
    for (int k = 0; k < 4; k++) s = fmaf(wsm[dd * 4 + k], tile[dd * 69 + ll + k], s);
    float sv = s / (1.f + __expf(-s));
    ub[(size_t)ll * D_SZ + dd] = sv;
  }
}

// ---------------------------------------------------------------------------
// K2: split-K GEMM1 partials.
// pssm[ks][bl][e] = sum_{d in slice ks} u[bl][d] * xw[e][d]
// ---------------------------------------------------------------------------
__global__ __launch_bounds__(256) void k2_gemm1(const float* __restrict__ u,
                                                const float* __restrict__ xw,
                                                float* __restrict__ pssm) {
  __shared__ __attribute__((aligned(16))) float aS[32 * 68];
  __shared__ __attribute__((aligned(16))) float bS[80 * 68];
  const int bl0 = blockIdx.x * 32, e0 = blockIdx.y * 80;
  const int kbase = blockIdx.z * (D_SZ / KS);
  const int tid = threadIdx.x;
  const int r2 = tid >> 4, c4 = tid & 15;
  float acc[2][5] = {};
  for (int k0 = kbase; k0 < kbase + D_SZ / KS; k0 += 64) {
    for (int i = tid; i < 32 * 16; i += 256) {
      int r = i >> 4, c = (i & 15) << 2;
      *(float4*)&aS[r * 68 + c] = *(const float4*)&u[(size_t)(bl0 + r) * D_SZ + k0 + c];
    }
    for (int i = tid; i < 80 * 16; i += 256) {
      int r = i >> 4, c = (i & 15) << 2;
      *(float4*)&bS[r * 68 + c] = *(const float4*)&xw[(size_t)(e0 + r) * D_SZ + k0 + c];
    }
    __syncthreads();
#pragma unroll 2
    for (int k = 0; k < 64; k += 4) {
      float4 a0 = *(float4*)&aS[(r2 * 2 + 0) * 68 + k];
      float4 a1 = *(float4*)&aS[(r2 * 2 + 1) * 68 + k];
#pragma unroll
      for (int j = 0; j < 5; ++j) {
        float4 bv = *(float4*)&bS[(c4 * 5 + j) * 68 + k];
        acc[0][j] = fmaf(a0.x, bv.x, acc[0][j]);
        acc[0][j] = fmaf(a0.y, bv.y, acc[0][j]);
        acc[0][j] = fmaf(a0.z, bv.z, acc[0][j]);
        acc[0][j] = fmaf(a0.w, bv.w, acc[0][j]);
        acc[1][j] = fmaf(a1.x, bv.x, acc[1][j]);
        acc[1][j] = fmaf(a1.y, bv.y, acc[1][j]);
        acc[1][j] = fmaf(a1.z, bv.z, acc[1][j]);
        acc[1][j] = fmaf(a1.w, bv.w, acc[1][j]);
      }
    }
    __syncthreads();
  }
  float* pb = pssm + (size_t)blockIdx.z * MROWS * E_SZ;
#pragma unroll
  for (int i = 0; i < 2; ++i) {
    size_t row = bl0 + r2 * 2 + i;
#pragma unroll
    for (int j = 0; j < 5; ++j)
      pb[row * E_SZ + e0 + c4 * 5 + j] = acc[i][j];
  }
}

// ---------------------------------------------------------------------------
// K3: reduce KS split-K partials + RMSNorm -> final ssm. one wave per row.
// ---------------------------------------------------------------------------
__global__ __launch_bounds__(256) void k3_rms(const float* __restrict__ pssm,
                                              float* __restrict__ ssm,
                                              const float* __restrict__ dtln,
                                              const float* __restrict__ bln,
                                              const float* __restrict__ cln) {
  const int lane = threadIdx.x & 63;
  const int wv = threadIdx.x >> 6;
  const size_t row = (size_t)blockIdx.x * 4 + wv;
  float v0 = 0.f, v1 = 0.f, v2 = 0.f;
#pragma unroll
  for (int ks = 0; ks < KS; ++ks) {
    const float* q = pssm + ((size_t)ks * MROWS + row) * E_SZ;
    v0 += q[lane];
    v1 += q[64 + lane];
    if (lane < 32) v2 += q[128 + lane];
  }
  float sdt = v0 * v0 + v1 * v1;
#pragma unroll
  for (int m = 1; m < 64; m <<= 1) sdt += __shfl_xor(sdt, m);
  float sv2 = v2 * v2;
#pragma unroll
  for (int m = 1; m < 16; m <<= 1) sv2 += __shfl_xor(sv2, m);
  float sB = __shfl(sv2, 0);
  float sC = __shfl(sv2, 16);
  float rdt = rsqrtf(sdt * (1.f / 128.f) + 1e-6f);
  float rB  = rsqrtf(sB  * (1.f / 16.f)  + 1e-6f);
  float rC  = rsqrtf(sC  * (1.f / 16.f)  + 1e-6f);
  float* p = ssm + row * E_SZ;
  p[lane]      = v0 * rdt * dtln[lane];
  p[64 + lane] = v1 * rdt * dtln[64 + lane];
  if (lane < 16)      p[128 + lane] = v2 * rB * bln[lane];
  else if (lane < 32) p[128 + lane] = v2 * rC * cln[lane - 16];
}

// ---------------------------------------------------------------------------
// K4: delta[bl][d] = softplus( dt @ dt_w^T + dt_b )  (M=4096, N=2048, K=128)
// ---------------------------------------------------------------------------
__global__ __launch_bounds__(256) void k4_gemm2(const float* __restrict__ ssm,
                                                const float* __restrict__ dtw,
                                                const float* __restrict__ dtb,
                                                float* __restrict__ delta) {
  __shared__ __attribute__((aligned(16))) float aS[64 * 68];
  __shared__ __attribute__((aligned(16))) float bS[64 * 68];
  const int bl0 = blockIdx.x * 64, d0 = blockIdx.y * 64;
  const int tid = threadIdx.x;
  const int r4 = tid >> 4, c4 = tid & 15;
  float acc[4][4] = {};
  for (int k0 = 0; k0 < R_SZ; k0 += 64) {
    for (int i = tid; i < 64 * 16; i += 256) {
      int r = i >> 4, c = (i & 15) << 2;
      *(float4*)&aS[r * 68 + c] = *(const float4*)&ssm[(size_t)(bl0 + r) * E_SZ + k0 + c];
    }
    for (int i = tid; i < 64 * 16; i += 256) {
      int r = i >> 4, c = (i & 15) << 2;
      *(float4*)&bS[r * 68 + c] = *(const float4*)&dtw[(size_t)(d0 + r) * R_SZ + k0 + c];
    }
    __syncthreads();
#pragma unroll 4
    for (int k = 0; k < 64; k += 4) {
      float4 av[4], bv[4];
#pragma unroll
      for (int i = 0; i < 4; i++) av[i] = *(float4*)&aS[(r4 * 4 + i) * 68 + k];
#pragma unroll
      for (int j = 0; j < 4; j++) bv[j] = *(float4*)&bS[(c4 + 16 * j) * 68 + k];
#pragma unroll
      for (int i = 0; i < 4; i++)
#pragma unroll
        for (int j = 0; j < 4; j++) {
          acc[i][j] = fmaf(av[i].x, bv[j].x, acc[i][j]);
          acc[i][j] = fmaf(av[i].y, bv[j].y, acc[i][j]);
          acc[i][j] = fmaf(av[i].z, bv[j].z, acc[i][j]);
          acc[i][j] = fmaf(av[i].w, bv[j].w, acc[i][j]);
        }
    }
    __syncthreads();
  }
#pragma unroll
  for (int i = 0; i < 4; i++) {
    size_t row = bl0 + r4 * 4 + i;
#pragma unroll
    for (int j = 0; j < 4; j++) {
      int d = d0 + c4 + 16 * j;
      float x = acc[i][j] + dtb[d];
      float sp = (x > 20.f) ? x : log1pf(__expf(x));
      delta[row * D_SZ + d] = sp;
    }
  }
}

// ---------------------------------------------------------------------------
// K5a: chunked scan, phase A. thread = (b, d, chunk), N=16 states in regs.
// B-tile staged in LDS (block-uniform); u/delta depth-1 prefetched.
// ---------------------------------------------------------------------------
__global__ __launch_bounds__(256) void k5a(const float* __restrict__ u,
                                           const float* __restrict__ delta,
                                           const float* __restrict__ ssm,
                                           const float* __restrict__ alog,
                                           float* __restrict__ chk,
                                           float* __restrict__ sumdt) {
  __shared__ __attribute__((aligned(16))) float Bs[CLEN * N_SZ];  // 1 KB
  const int tid = threadIdx.x;
  const int d = blockIdx.x * 256 + tid;
  const int c = blockIdx.y, b = blockIdx.z;
  const size_t l0 = (size_t)c * CLEN;
  const float* bp = ssm + ((size_t)b * L_SZ + l0) * E_SZ + R_SZ;
  if (tid < CLEN * N_SZ) {
    int t = tid >> 4, n = tid & 15;
    Bs[tid] = bp[(size_t)t * E_SZ + n];
  }
  float a[N_SZ], s[N_SZ];
#pragma unroll
  for (int i = 0; i < 4; i++) {
    float4 al = *(const float4*)&alog[(size_t)d * N_SZ + 4 * i];
    a[4 * i + 0] = -__expf(al.x); a[4 * i + 1] = -__expf(al.y);
    a[4 * i + 2] = -__expf(al.z); a[4 * i + 3] = -__expf(al.w);
  }
#pragma unroll
  for (int n = 0; n < N_SZ; n++) s[n] = 0.f;
  const float* dp = delta + ((size_t)b * L_SZ + l0) * D_SZ + d;
  const float* up = u     + ((size_t)b * L_SZ + l0) * D_SZ + d;
  __syncthreads();
  float sdt = 0.f;
  float dt = dp[0], ut = up[0];
#pragma unroll 4
  for (int t = 0; t < CLEN; ++t) {
    const int tn = (t + 1 < CLEN) ? t + 1 : t;
    float dt_n = dp[(size_t)tn * D_SZ];
    float ut_n = up[(size_t)tn * D_SZ];
    float du = dt * ut;
    sdt += dt;
#pragma unroll
    for (int n = 0; n < N_SZ; n++)
      s[n] = fmaf(__expf(a[n] * dt), s[n], du * Bs[t * N_SZ + n]);
    dt = dt_n; ut = ut_n;
  }
  float* cp = chk + (((size_t)b * CHN + c) * D_SZ + d) * N_SZ;
#pragma unroll
  for (int i = 0; i < 4; i++)
    *(float4*)&cp[4 * i] = make_float4(s[4 * i], s[4 * i + 1], s[4 * i + 2], s[4 * i + 3]);
  sumdt[((size_t)b * CHN + c) * D_SZ + d] = sdt;
}

// ---------------------------------------------------------------------------
// K5b: prefix over chunk summaries, in place. thread = (b, d, n).
// ---------------------------------------------------------------------------
__global__ __launch_bounds__(256) void k5b(const float* __restrict__ alog,
                                           const float* __restrict__ sumdt,
                                           float* __restrict__ chk) {
  const int g = blockIdx.x * 256 + threadIdx.x;      // over B*D*16 = 65536
  const int n = g & 15;
  const int d = (g >> 4) & (D_SZ - 1);
  const int b = g >> 15;
  const float a = -__expf(alog[(size_t)d * N_SZ + n]);
  float s = 0.f;
  float v  = chk[(((size_t)b * CHN) * D_SZ + d) * N_SZ + n];
  float sd = sumdt[((size_t)b * CHN) * D_SZ + d];
  for (int c = 0; c < CHN; ++c) {
    const int cn = (c + 1 < CHN) ? c + 1 : c;
    float v_n  = chk[(((size_t)b * CHN + cn) * D_SZ + d) * N_SZ + n];
    float sd_n = sumdt[((size_t)b * CHN + cn) * D_SZ + d];
    float init = s;
    s = fmaf(__expf(a * sd), s, v);
    chk[(((size_t)b * CHN + c) * D_SZ + d) * N_SZ + n] = init;
    v = v_n; sd = sd_n;
  }
}

// ---------------------------------------------------------------------------
// K5c: chunked scan, phase C. Re-run chunk from init state; fused y, skip, gate.
// B/C tiles staged in LDS; u/delta/gate depth-1 prefetched.
// ---------------------------------------------------------------------------
__global__ __launch_bounds__(256) void k5c(const float* __restrict__ u,
                                           const float* __restrict__ delta,
                                           const float* __restrict__ ssm,
                                           const float* __restrict__ gate,
                                           const float* __restrict__ alog,
                                           const float* __restrict__ dparam,
                                           const float* __restrict__ chk,
                                           float* __restrict__ out) {
  __shared__ __attribute__((aligned(16))) float Bs[CLEN * N_SZ];
  __shared__ __attribute__((aligned(16))) float Cs[CLEN * N_SZ];
  const int tid = threadIdx.x;
  const int d = blockIdx.x * 256 + tid;
  const int c = blockIdx.y, b = blockIdx.z;
  const size_t l0 = (size_t)c * CLEN;
  const float* bp = ssm + ((size_t)b * L_SZ + l0) * E_SZ + R_SZ;
  if (tid < CLEN * N_SZ) {
    int t = tid >> 4, n = tid & 15;
    Bs[tid] = bp[(size_t)t * E_SZ + n];
    Cs[tid] = bp[(size_t)t * E_SZ + N_SZ + n];
  }
  float a[N_SZ], s[N_SZ];
#pragma unroll
  for (int i = 0; i < 4; i++) {
    float4 al = *(const float4*)&alog[(size_t)d * N_SZ + 4 * i];
    a[4 * i + 0] = -__expf(al.x); a[4 * i + 1] = -__expf(al.y);
    a[4 * i + 2] = -__expf(al.z); a[4 * i + 3] = -__expf(al.w);
  }
  const float* cp = chk + (((size_t)b * CHN + c) * D_SZ + d) * N_SZ;
#pragma unroll
  for (int i = 0; i < 4; i++) {
    float4 sv = *(const float4*)&cp[4 * i];
    s[4 * i] = sv.x; s[4 * i + 1] = sv.y; s[4 * i + 2] = sv.z; s[4 * i + 3] = sv.w;
  }
  const float dpv = dparam[d];
  const float* dp = delta + ((size_t)b * L_SZ + l0) * D_SZ + d;
  const float* up = u     + ((size_t)b * L_SZ + l0) * D_SZ + d;
  const float* gp = gate  + ((size_t)b * D_SZ + d) * L_SZ + l0;
  float* op = out + ((size_t)b * L_SZ + l0) * D_SZ + d;
  __syncthreads();
  float dt = dp[0], ut = up[0], gv = gp[0];
#pragma unroll 4
  for (int t = 0; t < CLEN; ++t) {
    const int tn = (t + 1 < CLEN) ? t + 1 : t;
    float dt_n = dp[(size_t)tn * D_SZ];
    float ut_n = up[(size_t)tn * D_SZ];
    float gv_n = gp[tn];
    float du = dt * ut;
    float y = 0.f;
#pragma unroll
    for (int n = 0; n < N_SZ; n++) {
      s[n] = fmaf(__expf(a[n] * dt), s[n], du * Bs[t * N_SZ + n]);
      y = fmaf(s[n], Cs[t * N_SZ + n], y);
    }
    float sg = gv / (1.f + __expf(-gv));
    op[(size_t)t * D_SZ] = fmaf(ut, dpv, y) * sg;
    dt = dt_n; ut = ut_n; gv = gv_n;
  }
}

// ---------------------------------------------------------------------------
extern "C" void kernel_launch(void* const* d_in, const int* in_sizes, int n_in,
                              void* d_out, int out_size, void* d_ws, size_t ws_size,
                              hipStream_t stream) {
  const float* h    = (const float*)d_in[0];
  const float* gate = (const float*)d_in[1];
  const float* cw   = (const float*)d_in[2];
  const float* cb   = (const float*)d_in[3];
  const float* xw   = (const float*)d_in[4];
  const float* dtw  = (const float*)d_in[5];
  const float* dtb  = (const float*)d_in[6];
  const float* alog = (const float*)d_in[7];
  const float* dpar = (const float*)d_in[8];
  const float* dtln = (const float*)d_in[9];
  const float* bln  = (const float*)d_in[10];
  const float* cln  = (const float*)d_in[11];
  float* out = (float*)d_out;

  float* u     = (float*)d_ws;                               // B*L*D
  float* delta = u + (size_t)B_SZ * L_SZ * D_SZ;             // B*L*D (aliases pssm)
  float* pssm  = delta;                                      // KS*MROWS*E — dead before k4 writes delta
  float* ssm   = delta + (size_t)B_SZ * L_SZ * D_SZ;         // B*L*E
  float* chk   = ssm + (size_t)B_SZ * L_SZ * E_SZ;           // B*CHN*D*N
  float* sumdt = chk + (size_t)B_SZ * CHN * D_SZ * N_SZ;     // B*CHN*D

  hipLaunchKernelGGL(k1_conv, dim3(L_SZ / 64, D_SZ / 64, B_SZ), dim3(256), 0, stream,
                     h, cw, cb, u);
  hipLaunchKernelGGL(k2_gemm1, dim3(MROWS / 32, 2, KS), dim3(256), 0, stream,
                     u, xw, pssm);
  hipLaunchKernelGGL(k3_rms, dim3(MROWS / 4), dim3(256), 0, stream,
                     pssm, ssm, dtln, bln, cln);
  hipLaunchKernelGGL(k4_gemm2, dim3(MROWS / 64, D_SZ / 64), dim3(256), 0, stream,
                     ssm, dtw, dtb, delta);
  hipLaunchKernelGGL(k5a, dim3(D_SZ / 256, CHN, B_SZ), dim3(256), 0, stream,
                     u, delta, ssm, alog, chk, sumdt);
  hipLaunchKernelGGL(k5b, dim3((B_SZ * D_SZ * N_SZ) / 256), dim3(256), 0, stream,
                     alog, sumdt, chk);
  hipLaunchKernelGGL(k5c, dim3(D_SZ / 256, CHN, B_SZ), dim3(256), 0, stream,
                     u, delta, ssm, gate, alog, dpar, chk, out);
}

// Round 5
// 355.029 us; speedup vs baseline: 3.9149x; 1.0088x over previous
//
#include <hip/hip_runtime.h>
#include <cstdint>
#include <cstddef>

#define B_SZ 2
#define D_SZ 2048
#define L_SZ 2048
#define R_SZ 128
#define N_SZ 16
#define E_SZ (R_SZ + 2*N_SZ)   // 160
#define CHN 128                // chunks over L
#define CLEN 16                // L_SZ / CHN
#define KS 16                  // split-K factor for GEMM1 (slice = 128)
#define MROWS (B_SZ * L_SZ)    // 4096

// ---------------------------------------------------------------------------
// K1: causal depthwise conv1d (K=4) + bias + SiLU, with LDS transpose.
// ---------------------------------------------------------------------------
__global__ __launch_bounds__(256) void k1_conv(const float* __restrict__ h,
                                               const float* __restrict__ cw,
                                               const float* __restrict__ cb,
                                               float* __restrict__ u) {
  __shared__ __attribute__((aligned(16))) float tile[64 * 69];
  __shared__ float wsm[64 * 4];
  __shared__ float bsm[64];
  const int b = blockIdx.z, d0 = blockIdx.y * 64, l0 = blockIdx.x * 64;
  const int tid = threadIdx.x;
  if (tid < 64) {
    bsm[tid] = cb[d0 + tid];
#pragma unroll
    for (int k = 0; k < 4; k++) wsm[tid * 4 + k] = cw[(d0 + tid) * 4 + k];
  }
  const float* hb = h + ((size_t)b * D_SZ + d0) * L_SZ;
  for (int i = tid; i < 64 * 68; i += 256) {
    int r = i / 68, c = i - r * 68;
    int gl = l0 - 3 + c;
    float v = 0.f;
    if (c < 67 && gl >= 0) v = hb[(size_t)r * L_SZ + gl];
    tile[r * 69 + c] = v;
  }
  __syncthreads();
  float* ub = u + ((size_t)b * L_SZ + l0) * D_SZ + d0;
  for (int i = tid; i < 64 * 64; i += 256) {
    int ll = i >> 6, dd = i & 63;
    float s = bsm[dd];
#pragma unroll
    for (int k = 0; k < 4; k++) s = fmaf(wsm[dd * 4 + k], tile[dd * 69 + ll + k], s);
    float sv = s / (1.f + __expf(-s));
    ub[(size_t)ll * D_SZ + dd] = sv;
  }
}

// ---------------------------------------------------------------------------
// K2: split-K GEMM1 partials. pssm[ks][bl][e] = sum_{d in slice} u[bl][d]*xw[e][d]
// Tile 128 rows x 160 cols (full E), BK=32, 8x10 per thread (17.8 FMA/ds_read).
// grid (32, KS=16) = 512 blocks, LDS 41 KB -> 3 blocks/CU.
// ---------------------------------------------------------------------------
__global__ __launch_bounds__(256, 2) void k2_gemm1(const float* __restrict__ u,
                                                   const float* __restrict__ xw,
                                                   float* __restrict__ pssm) {
  __shared__ __attribute__((aligned(16))) float aS[128 * 36];
  __shared__ __attribute__((aligned(16))) float bS[160 * 36];
  const int bl0 = blockIdx.x * 128;
  const int kbase = blockIdx.y * (D_SZ / KS);   // slice = 128
  const int tid = threadIdx.x;
  const int rg = tid >> 4, c4 = tid & 15;       // rows rg*8..rg*8+7, cols c4+16j
  float acc[8][10] = {};
  for (int k0 = kbase; k0 < kbase + D_SZ / KS; k0 += 32) {
    for (int i = tid; i < 128 * 8; i += 256) {  // A: 128x32 floats as float4
      int r = i >> 3, c = (i & 7) << 2;
      *(float4*)&aS[r * 36 + c] = *(const float4*)&u[(size_t)(bl0 + r) * D_SZ + k0 + c];
    }
    for (int i = tid; i < 160 * 8; i += 256) {  // B: 160x32
      int r = i >> 3, c = (i & 7) << 2;
      *(float4*)&bS[r * 36 + c] = *(const float4*)&xw[(size_t)r * D_SZ + k0 + c];
    }
    __syncthreads();
#pragma unroll 2
    for (int k = 0; k < 32; k += 4) {
      float4 bv[10];
#pragma unroll
      for (int j = 0; j < 10; ++j) bv[j] = *(float4*)&bS[(c4 + 16 * j) * 36 + k];
#pragma unroll
      for (int i = 0; i < 8; ++i) {
        float4 av = *(float4*)&aS[(rg * 8 + i) * 36 + k];
#pragma unroll
        for (int j = 0; j < 10; ++j) {
          acc[i][j] = fmaf(av.x, bv[j].x, acc[i][j]);
          acc[i][j] = fmaf(av.y, bv[j].y, acc[i][j]);
          acc[i][j] = fmaf(av.z, bv[j].z, acc[i][j]);
          acc[i][j] = fmaf(av.w, bv[j].w, acc[i][j]);
        }
      }
    }
    __syncthreads();
  }
  float* pb = pssm + (size_t)blockIdx.y * MROWS * E_SZ;
#pragma unroll
  for (int i = 0; i < 8; ++i) {
    size_t row = bl0 + rg * 8 + i;
#pragma unroll
    for (int j = 0; j < 10; ++j)
      pb[row * E_SZ + c4 + 16 * j] = acc[i][j];
  }
}

// ---------------------------------------------------------------------------
// K3: reduce KS split-K partials + RMSNorm -> final ssm. one wave per row.
// ---------------------------------------------------------------------------
__global__ __launch_bounds__(256) void k3_rms(const float* __restrict__ pssm,
                                              float* __restrict__ ssm,
                                              const float* __restrict__ dtln,
                                              const float* __restrict__ bln,
                                              const float* __restrict__ cln) {
  const int lane = threadIdx.x & 63;
  const int wv = threadIdx.x >> 6;
  const size_t row = (size_t)blockIdx.x * 4 + wv;
  float v0 = 0.f, v1 = 0.f, v2 = 0.f;
#pragma unroll
  for (int ks = 0; ks < KS; ++ks) {
    const float* q = pssm + ((size_t)ks * MROWS + row) * E_SZ;
    v0 += q[lane];
    v1 += q[64 + lane];
    if (lane < 32) v2 += q[128 + lane];
  }
  float sdt = v0 * v0 + v1 * v1;
#pragma unroll
  for (int m = 1; m < 64; m <<= 1) sdt += __shfl_xor(sdt, m);
  float sv2 = v2 * v2;
#pragma unroll
  for (int m = 1; m < 16; m <<= 1) sv2 += __shfl_xor(sv2, m);
  float sB = __shfl(sv2, 0);
  float sC = __shfl(sv2, 16);
  float rdt = rsqrtf(sdt * (1.f / 128.f) + 1e-6f);
  float rB  = rsqrtf(sB  * (1.f / 16.f)  + 1e-6f);
  float rC  = rsqrtf(sC  * (1.f / 16.f)  + 1e-6f);
  float* p = ssm + row * E_SZ;
  p[lane]      = v0 * rdt * dtln[lane];
  p[64 + lane] = v1 * rdt * dtln[64 + lane];
  if (lane < 16)      p[128 + lane] = v2 * rB * bln[lane];
  else if (lane < 32) p[128 + lane] = v2 * rC * cln[lane - 16];
}

// ---------------------------------------------------------------------------
// K4: delta = softplus(dt @ dt_w^T + dt_b). M=4096, N=2048, K=128.
// Tile 128x128, BK=32, 8x8 per thread (16 FMA/ds_read). grid (32,16) = 512.
// ---------------------------------------------------------------------------
__global__ __launch_bounds__(256, 2) void k4_gemm2(const float* __restrict__ ssm,
                                                   const float* __restrict__ dtw,
                                                   const float* __restrict__ dtb,
                                                   float* __restrict__ delta) {
  __shared__ __attribute__((aligned(16))) float aS[128 * 36];
  __shared__ __attribute__((aligned(16))) float bS[128 * 36];
  const int bl0 = blockIdx.x * 128, d0 = blockIdx.y * 128;
  const int tid = threadIdx.x;
  const int rg = tid >> 4, c4 = tid & 15;
  float acc[8][8] = {};
  for (int k0 = 0; k0 < R_SZ; k0 += 32) {
    for (int i = tid; i < 128 * 8; i += 256) {
      int r = i >> 3, c = (i & 7) << 2;
      *(float4*)&aS[r * 36 + c] = *(const float4*)&ssm[(size_t)(bl0 + r) * E_SZ + k0 + c];
    }
    for (int i = tid; i < 128 * 8; i += 256) {
      int r = i >> 3, c = (i & 7) << 2;
      *(float4*)&bS[r * 36 + c] = *(const float4*)&dtw[(size_t)(d0 + r) * R_SZ + k0 + c];
    }
    __syncthreads();
#pragma unroll 2
    for (int k = 0; k < 32; k += 4) {
      float4 bv[8];
#pragma unroll
      for (int j = 0; j < 8; ++j) bv[j] = *(float4*)&bS[(c4 + 16 * j) * 36 + k];
#pragma unroll
      for (int i = 0; i < 8; ++i) {
        float4 av = *(float4*)&aS[(rg * 8 + i) * 36 + k];
#pragma unroll
        for (int j = 0; j < 8; ++j) {
          acc[i][j] = fmaf(av.x, bv[j].x, acc[i][j]);
          acc[i][j] = fmaf(av.y, bv[j].y, acc[i][j]);
          acc[i][j] = fmaf(av.z, bv[j].z, acc[i][j]);
          acc[i][j] = fmaf(av.w, bv[j].w, acc[i][j]);
        }
      }
    }
    __syncthreads();
  }
#pragma unroll
  for (int i = 0; i < 8; ++i) {
    size_t row = bl0 + rg * 8 + i;
#pragma unroll
    for (int j = 0; j < 8; ++j) {
      int d = d0 + c4 + 16 * j;
      float x = acc[i][j] + dtb[d];
      float sp = (x > 20.f) ? x : log1pf(__expf(x));
      delta[row * D_SZ + d] = sp;
    }
  }
}

// ---------------------------------------------------------------------------
// K5a: chunked scan, phase A. thread = (b, d, chunk), N=16 states in regs.
// ---------------------------------------------------------------------------
__global__ __launch_bounds__(256) void k5a(const float* __restrict__ u,
                                           const float* __restrict__ delta,
                                           const float* __restrict__ ssm,
                                           const float* __restrict__ alog,
                                           float* __restrict__ chk,
                                           float* __restrict__ sumdt) {
  __shared__ __attribute__((aligned(16))) float Bs[CLEN * N_SZ];  // 1 KB
  const int tid = threadIdx.x;
  const int d = blockIdx.x * 256 + tid;
  const int c = blockIdx.y, b = blockIdx.z;
  const size_t l0 = (size_t)c * CLEN;
  const float* bp = ssm + ((size_t)b * L_SZ + l0) * E_SZ + R_SZ;
  if (tid < CLEN * N_SZ) {
    int t = tid >> 4, n = tid & 15;
    Bs[tid] = bp[(size_t)t * E_SZ + n];
  }
  float a[N_SZ], s[N_SZ];
#pragma unroll
  for (int i = 0; i < 4; i++) {
    float4 al = *(const float4*)&alog[(size_t)d * N_SZ + 4 * i];
    a[4 * i + 0] = -__expf(al.x); a[4 * i + 1] = -__expf(al.y);
    a[4 * i + 2] = -__expf(al.z); a[4 * i + 3] = -__expf(al.w);
  }
#pragma unroll
  for (int n = 0; n < N_SZ; n++) s[n] = 0.f;
  const float* dp = delta + ((size_t)b * L_SZ + l0) * D_SZ + d;
  const float* up = u     + ((size_t)b * L_SZ + l0) * D_SZ + d;
  __syncthreads();
  float sdt = 0.f;
  float dt = dp[0], ut = up[0];
#pragma unroll 4
  for (int t = 0; t < CLEN; ++t) {
    const int tn = (t + 1 < CLEN) ? t + 1 : t;
    float dt_n = dp[(size_t)tn * D_SZ];
    float ut_n = up[(size_t)tn * D_SZ];
    float du = dt * ut;
    sdt += dt;
#pragma unroll
    for (int n = 0; n < N_SZ; n++)
      s[n] = fmaf(__expf(a[n] * dt), s[n], du * Bs[t * N_SZ + n]);
    dt = dt_n; ut = ut_n;
  }
  float* cp = chk + (((size_t)b * CHN + c) * D_SZ + d) * N_SZ;
#pragma unroll
  for (int i = 0; i < 4; i++)
    *(float4*)&cp[4 * i] = make_float4(s[4 * i], s[4 * i + 1], s[4 * i + 2], s[4 * i + 3]);
  sumdt[((size_t)b * CHN + c) * D_SZ + d] = sdt;
}

// ---------------------------------------------------------------------------
// K5b: prefix over chunk summaries, in place. thread = (b, d, n).
// ---------------------------------------------------------------------------
__global__ __launch_bounds__(256) void k5b(const float* __restrict__ alog,
                                           const float* __restrict__ sumdt,
                                           float* __restrict__ chk) {
  const int g = blockIdx.x * 256 + threadIdx.x;      // over B*D*16 = 65536
  const int n = g & 15;
  const int d = (g >> 4) & (D_SZ - 1);
  const int b = g >> 15;
  const float a = -__expf(alog[(size_t)d * N_SZ + n]);
  float s = 0.f;
  float v  = chk[(((size_t)b * CHN) * D_SZ + d) * N_SZ + n];
  float sd = sumdt[((size_t)b * CHN) * D_SZ + d];
  for (int c = 0; c < CHN; ++c) {
    const int cn = (c + 1 < CHN) ? c + 1 : c;
    float v_n  = chk[(((size_t)b * CHN + cn) * D_SZ + d) * N_SZ + n];
    float sd_n = sumdt[((size_t)b * CHN + cn) * D_SZ + d];
    float init = s;
    s = fmaf(__expf(a * sd), s, v);
    chk[(((size_t)b * CHN + c) * D_SZ + d) * N_SZ + n] = init;
    v = v_n; sd = sd_n;
  }
}

// ---------------------------------------------------------------------------
// K5c: chunked scan, phase C. Re-run chunk from init state; fused y, skip, gate.
// ---------------------------------------------------------------------------
__global__ __launch_bounds__(256) void k5c(const float* __restrict__ u,
                                           const float* __restrict__ delta,
                                           const float* __restrict__ ssm,
                                           const float* __restrict__ gate,
                                           const float* __restrict__ alog,
                                           const float* __restrict__ dparam,
                                           const float* __restrict__ chk,
                                           float* __restrict__ out) {
  __shared__ __attribute__((aligned(16))) float Bs[CLEN * N_SZ];
  __shared__ __attribute__((aligned(16))) float Cs[CLEN * N_SZ];
  const int tid = threadIdx.x;
  const int d = blockIdx.x * 256 + tid;
  const int c = blockIdx.y, b = blockIdx.z;
  const size_t l0 = (size_t)c * CLEN;
  const float* bp = ssm + ((size_t)b * L_SZ + l0) * E_SZ + R_SZ;
  if (tid < CLEN * N_SZ) {
    int t = tid >> 4, n = tid & 15;
    Bs[tid] = bp[(size_t)t * E_SZ + n];
    Cs[tid] = bp[(size_t)t * E_SZ + N_SZ + n];
  }
  float a[N_SZ], s[N_SZ];
#pragma unroll
  for (int i = 0; i < 4; i++) {
    float4 al = *(const float4*)&alog[(size_t)d * N_SZ + 4 * i];
    a[4 * i + 0] = -__expf(al.x); a[4 * i + 1] = -__expf(al.y);
    a[4 * i + 2] = -__expf(al.z); a[4 * i + 3] = -__expf(al.w);
  }
  const float* cp = chk + (((size_t)b * CHN + c) * D_SZ + d) * N_SZ;
#pragma unroll
  for (int i = 0; i < 4; i++) {
    float4 sv = *(const float4*)&cp[4 * i];
    s[4 * i] = sv.x; s[4 * i + 1] = sv.y; s[4 * i + 2] = sv.z; s[4 * i + 3] = sv.w;
  }
  const float dpv = dparam[d];
  const float* dp = delta + ((size_t)b * L_SZ + l0) * D_SZ + d;
  const float* up = u     + ((size_t)b * L_SZ + l0) * D_SZ + d;
  const float* gp = gate  + ((size_t)b * D_SZ + d) * L_SZ + l0;
  float* op = out + ((size_t)b * L_SZ + l0) * D_SZ + d;
  __syncthreads();
  float dt = dp[0], ut = up[0], gv = gp[0];
#pragma unroll 4
  for (int t = 0; t < CLEN; ++t) {
    const int tn = (t + 1 < CLEN) ? t + 1 : t;
    float dt_n = dp[(size_t)tn * D_SZ];
    float ut_n = up[(size_t)tn * D_SZ];
    float gv_n = gp[tn];
    float du = dt * ut;
    float y = 0.f;
#pragma unroll
    for (int n = 0; n < N_SZ; n++) {
      s[n] = fmaf(__expf(a[n] * dt), s[n], du * Bs[t * N_SZ + n]);
      y = fmaf(s[n], Cs[t * N_SZ + n], y);
    }
    float sg = gv / (1.f + __expf(-gv));
    op[(size_t)t * D_SZ] = fmaf(ut, dpv, y) * sg;
    dt = dt_n; ut = ut_n; gv = gv_n;
  }
}

// ---------------------------------------------------------------------------
extern "C" void kernel_launch(void* const* d_in, const int* in_sizes, int n_in,
                              void* d_out, int out_size, void* d_ws, size_t ws_size,
                              hipStream_t stream) {
  const float* h    = (const float*)d_in[0];
  const float* gate = (const float*)d_in[1];
  const float* cw   = (const float*)d_in[2];
  const float* cb   = (const float*)d_in[3];
  const float* xw   = (const float*)d_in[4];
  const float* dtw  = (const float*)d_in[5];
  const float* dtb  = (const float*)d_in[6];
  const float* alog = (const float*)d_in[7];
  const float* dpar = (const float*)d_in[8];
  const float* dtln = (const float*)d_in[9];
  const float* bln  = (const float*)d_in[10];
  const float* cln  = (const float*)d_in[11];
  float* out = (float*)d_out;

  float* u     = (float*)d_ws;                               // B*L*D
  float* delta = u + (size_t)B_SZ * L_SZ * D_SZ;             // B*L*D
  float* ssm   = delta + (size_t)B_SZ * L_SZ * D_SZ;         // B*L*E
  float* chk   = ssm + (size_t)B_SZ * L_SZ * E_SZ;           // B*CHN*D*N (67 MB)
  float* sumdt = chk + (size_t)B_SZ * CHN * D_SZ * N_SZ;     // B*CHN*D
  // pssm (KS*MROWS*E = 42 MB) aliases chk: pssm is dead after k3; chk is
  // first written by k5a, which runs after k3 in stream order.
  float* pssm  = chk;

  hipLaunchKernelGGL(k1_conv, dim3(L_SZ / 64, D_SZ / 64, B_SZ), dim3(256), 0, stream,
                     h, cw, cb, u);
  hipLaunchKernelGGL(k2_gemm1, dim3(MROWS / 128, KS), dim3(256), 0, stream,
                     u, xw, pssm);
  hipLaunchKernelGGL(k3_rms, dim3(MROWS / 4), dim3(256), 0, stream,
                     pssm, ssm, dtln, bln, cln);
  hipLaunchKernelGGL(k4_gemm2, dim3(MROWS / 128, D_SZ / 128), dim3(256), 0, stream,
                     ssm, dtw, dtb, delta);
  hipLaunchKernelGGL(k5a, dim3(D_SZ / 256, CHN, B_SZ), dim3(256), 0, stream,
                     u, delta, ssm, alog, chk, sumdt);
  hipLaunchKernelGGL(k5b, dim3((B_SZ * D_SZ * N_SZ) / 256), dim3(256), 0, stream,
                     alog, sumdt, chk);
  hipLaunchKernelGGL(k5c, dim3(D_SZ / 256, CHN, B_SZ), dim3(256), 0, stream,
                     u, delta, ssm, gate, alog, dpar, chk, out);
}

// Round 6
// 294.037 us; speedup vs baseline: 4.7269x; 1.2074x over previous
//
#include <hip/hip_runtime.h>
#include <cstdint>
#include <cstddef>

#define B_SZ 2
#define D_SZ 2048
#define L_SZ 2048
#define R_SZ 128
#define N_SZ 16
#define E_SZ (R_SZ + 2*N_SZ)   // 160
#define CHN 128                // chunks over L
#define CLEN 16                // L_SZ / CHN
#define KS 16                  // split-K factor for GEMM1 (slice = 128)
#define MROWS (B_SZ * L_SZ)    // 4096

typedef __bf16 bf16;
typedef __bf16 bf16x4 __attribute__((ext_vector_type(4)));
typedef __bf16 bf16x8 __attribute__((ext_vector_type(8)));
typedef float  f32x4  __attribute__((ext_vector_type(4)));

// ---------------------------------------------------------------------------
// K0: fp32 -> bf16 cast (weights). n4 = n/4.
// ---------------------------------------------------------------------------
__global__ __launch_bounds__(256) void k0_cast(const float* __restrict__ src,
                                               bf16* __restrict__ dst, int n4) {
  int i = blockIdx.x * 256 + threadIdx.x;
  if (i < n4) {
    float4 v = ((const float4*)src)[i];
    bf16x4 o = { (bf16)v.x, (bf16)v.y, (bf16)v.z, (bf16)v.w };
    *(bf16x4*)&dst[4 * i] = o;
  }
}

// ---------------------------------------------------------------------------
// K1: causal depthwise conv1d (K=4) + bias + SiLU, LDS transpose.
// writes u (fp32, for scan) and ubf (bf16, for GEMM1).
// ---------------------------------------------------------------------------
__global__ __launch_bounds__(256) void k1_conv(const float* __restrict__ h,
                                               const float* __restrict__ cw,
                                               const float* __restrict__ cb,
                                               float* __restrict__ u,
                                               bf16* __restrict__ ubf) {
  __shared__ __attribute__((aligned(16))) float tile[64 * 69];
  __shared__ float wsm[64 * 4];
  __shared__ float bsm[64];
  const int b = blockIdx.z, d0 = blockIdx.y * 64, l0 = blockIdx.x * 64;
  const int tid = threadIdx.x;
  if (tid < 64) {
    bsm[tid] = cb[d0 + tid];
#pragma unroll
    for (int k = 0; k < 4; k++) wsm[tid * 4 + k] = cw[(d0 + tid) * 4 + k];
  }
  const float* hb = h + ((size_t)b * D_SZ + d0) * L_SZ;
  for (int i = tid; i < 64 * 68; i += 256) {
    int r = i / 68, c = i - r * 68;
    int gl = l0 - 3 + c;
    float v = 0.f;
    if (c < 67 && gl >= 0) v = hb[(size_t)r * L_SZ + gl];
    tile[r * 69 + c] = v;
  }
  __syncthreads();
  const size_t base = ((size_t)b * L_SZ + l0) * D_SZ + d0;
  for (int i = tid; i < 64 * 64; i += 256) {
    int ll = i >> 6, dd = i & 63;
    float s = bsm[dd];
#pragma unroll
    for (int k = 0; k < 4; k++) s = fmaf(wsm[dd * 4 + k], tile[dd * 69 + ll + k], s);
    float sv = s / (1.f + __expf(-s));
    u[base + (size_t)ll * D_SZ + dd] = sv;
    ubf[base + (size_t)ll * D_SZ + dd] = (bf16)sv;
  }
}

// ---------------------------------------------------------------------------
// K2: split-K GEMM1 via bf16 MFMA. pssm[ks][bl][e] (bf16 partials).
// Block: 128(M=bl) x 160(N=e full), K-slice 128 (BK=64 x2). grid (32, 16).
// Wave w: rows w*32..w*32+31 (2 m-tiles) x 10 e-tiles.
// ---------------------------------------------------------------------------
__global__ __launch_bounds__(256) void k2_gemm1(const bf16* __restrict__ ubf,
                                                const bf16* __restrict__ xwbf,
                                                bf16* __restrict__ pssm) {
  __shared__ __attribute__((aligned(16))) bf16 aS[128 * 72];
  __shared__ __attribute__((aligned(16))) bf16 bS[160 * 72];
  const int bl0 = blockIdx.x * 128;
  const int kbase = blockIdx.y * (D_SZ / KS);   // slice = 128
  const int tid = threadIdx.x;
  const int wv = tid >> 6, lane = tid & 63;
  const int ml = lane & 15, quad = lane >> 4;
  f32x4 acc[2][10] = {};
  for (int k0 = kbase; k0 < kbase + D_SZ / KS; k0 += 64) {
    for (int i = tid; i < 1024; i += 256) {          // A: 128x64 bf16
      int r = i >> 3, c = (i & 7) * 8;
      *(uint4*)&aS[r * 72 + c] = *(const uint4*)&ubf[(size_t)(bl0 + r) * D_SZ + k0 + c];
    }
    for (int i = tid; i < 1280; i += 256) {          // B: 160x64 bf16
      int r = i >> 3, c = (i & 7) * 8;
      *(uint4*)&bS[r * 72 + c] = *(const uint4*)&xwbf[(size_t)r * D_SZ + k0 + c];
    }
    __syncthreads();
#pragma unroll
    for (int ks = 0; ks < 2; ++ks) {
      bf16x8 af0 = *(const bf16x8*)&aS[(wv * 32 + ml) * 72 + ks * 32 + quad * 8];
      bf16x8 af1 = *(const bf16x8*)&aS[(wv * 32 + 16 + ml) * 72 + ks * 32 + quad * 8];
#pragma unroll
      for (int j = 0; j < 10; ++j) {
        bf16x8 bfv = *(const bf16x8*)&bS[(j * 16 + ml) * 72 + ks * 32 + quad * 8];
        acc[0][j] = __builtin_amdgcn_mfma_f32_16x16x32_bf16(af0, bfv, acc[0][j], 0, 0, 0);
        acc[1][j] = __builtin_amdgcn_mfma_f32_16x16x32_bf16(af1, bfv, acc[1][j], 0, 0, 0);
      }
    }
    __syncthreads();
  }
  bf16* pb = pssm + (size_t)blockIdx.y * MROWS * E_SZ;
#pragma unroll
  for (int mi = 0; mi < 2; ++mi)
#pragma unroll
    for (int j = 0; j < 10; ++j)
#pragma unroll
      for (int r = 0; r < 4; ++r) {
        int row = bl0 + wv * 32 + mi * 16 + quad * 4 + r;   // C/D: row=quad*4+reg
        pb[(size_t)row * E_SZ + j * 16 + ml] = (bf16)acc[mi][j][r];  // col=lane&15
      }
}

// ---------------------------------------------------------------------------
// K3: reduce KS bf16 partials + RMSNorm. dt -> dtbf (bf16 [4096][128]);
// B/C -> ssm fp32 (offsets 128..160 of each row). one wave per row.
// ---------------------------------------------------------------------------
__global__ __launch_bounds__(256) void k3_rms(const bf16* __restrict__ pssm,
                                              float* __restrict__ ssm,
                                              bf16* __restrict__ dtbf,
                                              const float* __restrict__ dtln,
                                              const float* __restrict__ bln,
                                              const float* __restrict__ cln) {
  const int lane = threadIdx.x & 63;
  const int wv = threadIdx.x >> 6;
  const size_t row = (size_t)blockIdx.x * 4 + wv;
  float v0 = 0.f, v1 = 0.f, v2 = 0.f;
#pragma unroll
  for (int ks = 0; ks < KS; ++ks) {
    const bf16* q = pssm + ((size_t)ks * MROWS + row) * E_SZ;
    v0 += (float)q[lane];
    v1 += (float)q[64 + lane];
    if (lane < 32) v2 += (float)q[128 + lane];
  }
  float sdt = v0 * v0 + v1 * v1;
#pragma unroll
  for (int m = 1; m < 64; m <<= 1) sdt += __shfl_xor(sdt, m);
  float sv2 = v2 * v2;
#pragma unroll
  for (int m = 1; m < 16; m <<= 1) sv2 += __shfl_xor(sv2, m);
  float sB = __shfl(sv2, 0);
  float sC = __shfl(sv2, 16);
  float rdt = rsqrtf(sdt * (1.f / 128.f) + 1e-6f);
  float rB  = rsqrtf(sB  * (1.f / 16.f)  + 1e-6f);
  float rC  = rsqrtf(sC  * (1.f / 16.f)  + 1e-6f);
  dtbf[row * R_SZ + lane]      = (bf16)(v0 * rdt * dtln[lane]);
  dtbf[row * R_SZ + 64 + lane] = (bf16)(v1 * rdt * dtln[64 + lane]);
  float* p = ssm + row * E_SZ;
  if (lane < 16)      p[128 + lane] = v2 * rB * bln[lane];
  else if (lane < 32) p[128 + lane] = v2 * rC * cln[lane - 16];
}

// ---------------------------------------------------------------------------
// K4: delta = softplus(dt @ dt_w^T + dt_b) via bf16 MFMA.
// M=4096, N=2048, K=128. Block 64x128, BK=64 x2, wave tile 32x64.
// grid (64, 16) = 1024 blocks, LDS 27.6 KB.
// ---------------------------------------------------------------------------
__global__ __launch_bounds__(256) void k4_gemm2(const bf16* __restrict__ dtbf,
                                                const bf16* __restrict__ dtwbf,
                                                const float* __restrict__ dtb,
                                                float* __restrict__ delta) {
  __shared__ __attribute__((aligned(16))) bf16 aS[64 * 72];
  __shared__ __attribute__((aligned(16))) bf16 bS[128 * 72];
  const int bl0 = blockIdx.x * 64, d0 = blockIdx.y * 128;
  const int tid = threadIdx.x;
  const int wv = tid >> 6, lane = tid & 63;
  const int ml = lane & 15, quad = lane >> 4;
  const int wm = (wv >> 1) * 32, wn = (wv & 1) * 64;
  f32x4 acc[2][4] = {};
  for (int k0 = 0; k0 < R_SZ; k0 += 64) {
    for (int i = tid; i < 512; i += 256) {           // A: 64x64 bf16
      int r = i >> 3, c = (i & 7) * 8;
      *(uint4*)&aS[r * 72 + c] = *(const uint4*)&dtbf[(size_t)(bl0 + r) * R_SZ + k0 + c];
    }
    for (int i = tid; i < 1024; i += 256) {          // B: 128x64 bf16
      int r = i >> 3, c = (i & 7) * 8;
      *(uint4*)&bS[r * 72 + c] = *(const uint4*)&dtwbf[(size_t)(d0 + r) * R_SZ + k0 + c];
    }
    __syncthreads();
#pragma unroll
    for (int ks = 0; ks < 2; ++ks) {
      bf16x8 af[2], bfv[4];
#pragma unroll
      for (int mi = 0; mi < 2; ++mi)
        af[mi] = *(const bf16x8*)&aS[(wm + mi * 16 + ml) * 72 + ks * 32 + quad * 8];
#pragma unroll
      for (int nj = 0; nj < 4; ++nj)
        bfv[nj] = *(const bf16x8*)&bS[(wn + nj * 16 + ml) * 72 + ks * 32 + quad * 8];
#pragma unroll
      for (int mi = 0; mi < 2; ++mi)
#pragma unroll
        for (int nj = 0; nj < 4; ++nj)
          acc[mi][nj] = __builtin_amdgcn_mfma_f32_16x16x32_bf16(af[mi], bfv[nj], acc[mi][nj], 0, 0, 0);
    }
    __syncthreads();
  }
#pragma unroll
  for (int nj = 0; nj < 4; ++nj) {
    const int d = d0 + wn + nj * 16 + ml;
    const float bias = dtb[d];
#pragma unroll
    for (int mi = 0; mi < 2; ++mi)
#pragma unroll
      for (int r = 0; r < 4; ++r) {
        int row = bl0 + wm + mi * 16 + quad * 4 + r;
        float x = acc[mi][nj][r] + bias;
        float sp = (x > 20.f) ? x : log1pf(__expf(x));
        delta[(size_t)row * D_SZ + d] = sp;
      }
  }
}

// ---------------------------------------------------------------------------
// K5a: chunked scan, phase A. thread = (b, d, chunk), N=16 states in regs.
// ---------------------------------------------------------------------------
__global__ __launch_bounds__(256) void k5a(const float* __restrict__ u,
                                           const float* __restrict__ delta,
                                           const float* __restrict__ ssm,
                                           const float* __restrict__ alog,
                                           float* __restrict__ chk,
                                           float* __restrict__ sumdt) {
  __shared__ __attribute__((aligned(16))) float Bs[CLEN * N_SZ];  // 1 KB
  const int tid = threadIdx.x;
  const int d = blockIdx.x * 256 + tid;
  const int c = blockIdx.y, b = blockIdx.z;
  const size_t l0 = (size_t)c * CLEN;
  const float* bp = ssm + ((size_t)b * L_SZ + l0) * E_SZ + R_SZ;
  if (tid < CLEN * N_SZ) {
    int t = tid >> 4, n = tid & 15;
    Bs[tid] = bp[(size_t)t * E_SZ + n];
  }
  float a[N_SZ], s[N_SZ];
#pragma unroll
  for (int i = 0; i < 4; i++) {
    float4 al = *(const float4*)&alog[(size_t)d * N_SZ + 4 * i];
    a[4 * i + 0] = -__expf(al.x); a[4 * i + 1] = -__expf(al.y);
    a[4 * i + 2] = -__expf(al.z); a[4 * i + 3] = -__expf(al.w);
  }
#pragma unroll
  for (int n = 0; n < N_SZ; n++) s[n] = 0.f;
  const float* dp = delta + ((size_t)b * L_SZ + l0) * D_SZ + d;
  const float* up = u     + ((size_t)b * L_SZ + l0) * D_SZ + d;
  __syncthreads();
  float sdt = 0.f;
  float dt = dp[0], ut = up[0];
#pragma unroll 4
  for (int t = 0; t < CLEN; ++t) {
    const int tn = (t + 1 < CLEN) ? t + 1 : t;
    float dt_n = dp[(size_t)tn * D_SZ];
    float ut_n = up[(size_t)tn * D_SZ];
    float du = dt * ut;
    sdt += dt;
#pragma unroll
    for (int n = 0; n < N_SZ; n++)
      s[n] = fmaf(__expf(a[n] * dt), s[n], du * Bs[t * N_SZ + n]);
    dt = dt_n; ut = ut_n;
  }
  float* cp = chk + (((size_t)b * CHN + c) * D_SZ + d) * N_SZ;
#pragma unroll
  for (int i = 0; i < 4; i++)
    *(float4*)&cp[4 * i] = make_float4(s[4 * i], s[4 * i + 1], s[4 * i + 2], s[4 * i + 3]);
  sumdt[((size_t)b * CHN + c) * D_SZ + d] = sdt;
}

// ---------------------------------------------------------------------------
// K5b: prefix over chunk summaries, in place. thread = (b, d, n).
// ---------------------------------------------------------------------------
__global__ __launch_bounds__(256) void k5b(const float* __restrict__ alog,
                                           const float* __restrict__ sumdt,
                                           float* __restrict__ chk) {
  const int g = blockIdx.x * 256 + threadIdx.x;      // over B*D*16 = 65536
  const int n = g & 15;
  const int d = (g >> 4) & (D_SZ - 1);
  const int b = g >> 15;
  const float a = -__expf(alog[(size_t)d * N_SZ + n]);
  float s = 0.f;
  float v  = chk[(((size_t)b * CHN) * D_SZ + d) * N_SZ + n];
  float sd = sumdt[((size_t)b * CHN) * D_SZ + d];
  for (int c = 0; c < CHN; ++c) {
    const int cn = (c + 1 < CHN) ? c + 1 : c;
    float v_n  = chk[(((size_t)b * CHN + cn) * D_SZ + d) * N_SZ + n];
    float sd_n = sumdt[((size_t)b * CHN + cn) * D_SZ + d];
    float init = s;
    s = fmaf(__expf(a * sd), s, v);
    chk[(((size_t)b * CHN + c) * D_SZ + d) * N_SZ + n] = init;
    v = v_n; sd = sd_n;
  }
}

// ---------------------------------------------------------------------------
// K5c: chunked scan, phase C. Re-run chunk from init state; fused y, skip, gate.
// ---------------------------------------------------------------------------
__global__ __launch_bounds__(256) void k5c(const float* __restrict__ u,
                                           const float* __restrict__ delta,
                                           const float* __restrict__ ssm,
                                           const float* __restrict__ gate,
                                           const float* __restrict__ alog,
                                           const float* __restrict__ dparam,
                                           const float* __restrict__ chk,
                                           float* __restrict__ out) {
  __shared__ __attribute__((aligned(16))) float Bs[CLEN * N_SZ];
  __shared__ __attribute__((aligned(16))) float Cs[CLEN * N_SZ];
  const int tid = threadIdx.x;
  const int d = blockIdx.x * 256 + tid;
  const int c = blockIdx.y, b = blockIdx.z;
  const size_t l0 = (size_t)c * CLEN;
  const float* bp = ssm + ((size_t)b * L_SZ + l0) * E_SZ + R_SZ;
  if (tid < CLEN * N_SZ) {
    int t = tid >> 4, n = tid & 15;
    Bs[tid] = bp[(size_t)t * E_SZ + n];
    Cs[tid] = bp[(size_t)t * E_SZ + N_SZ + n];
  }
  float a[N_SZ], s[N_SZ];
#pragma unroll
  for (int i = 0; i < 4; i++) {
    float4 al = *(const float4*)&alog[(size_t)d * N_SZ + 4 * i];
    a[4 * i + 0] = -__expf(al.x); a[4 * i + 1] = -__expf(al.y);
    a[4 * i + 2] = -__expf(al.z); a[4 * i + 3] = -__expf(al.w);
  }
  const float* cp = chk + (((size_t)b * CHN + c) * D_SZ + d) * N_SZ;
#pragma unroll
  for (int i = 0; i < 4; i++) {
    float4 sv = *(const float4*)&cp[4 * i];
    s[4 * i] = sv.x; s[4 * i + 1] = sv.y; s[4 * i + 2] = sv.z; s[4 * i + 3] = sv.w;
  }
  const float dpv = dparam[d];
  const float* dp = delta + ((size_t)b * L_SZ + l0) * D_SZ + d;
  const float* up = u     + ((size_t)b * L_SZ + l0) * D_SZ + d;
  const float* gp = gate  + ((size_t)b * D_SZ + d) * L_SZ + l0;
  float* op = out + ((size_t)b * L_SZ + l0) * D_SZ + d;
  __syncthreads();
  float dt = dp[0], ut = up[0], gv = gp[0];
#pragma unroll 4
  for (int t = 0; t < CLEN; ++t) {
    const int tn = (t + 1 < CLEN) ? t + 1 : t;
    float dt_n = dp[(size_t)tn * D_SZ];
    float ut_n = up[(size_t)tn * D_SZ];
    float gv_n = gp[tn];
    float du = dt * ut;
    float y = 0.f;
#pragma unroll
    for (int n = 0; n < N_SZ; n++) {
      s[n] = fmaf(__expf(a[n] * dt), s[n], du * Bs[t * N_SZ + n]);
      y = fmaf(s[n], Cs[t * N_SZ + n], y);
    }
    float sg = gv / (1.f + __expf(-gv));
    op[(size_t)t * D_SZ] = fmaf(ut, dpv, y) * sg;
    dt = dt_n; ut = ut_n; gv = gv_n;
  }
}

// ---------------------------------------------------------------------------
extern "C" void kernel_launch(void* const* d_in, const int* in_sizes, int n_in,
                              void* d_out, int out_size, void* d_ws, size_t ws_size,
                              hipStream_t stream) {
  const float* h    = (const float*)d_in[0];
  const float* gate = (const float*)d_in[1];
  const float* cw   = (const float*)d_in[2];
  const float* cb   = (const float*)d_in[3];
  const float* xw   = (const float*)d_in[4];
  const float* dtw  = (const float*)d_in[5];
  const float* dtb  = (const float*)d_in[6];
  const float* alog = (const float*)d_in[7];
  const float* dpar = (const float*)d_in[8];
  const float* dtln = (const float*)d_in[9];
  const float* bln  = (const float*)d_in[10];
  const float* cln  = (const float*)d_in[11];
  float* out = (float*)d_out;

  // Workspace layout (floats). Proven extent from R5: 27.93M floats; here 26.9M.
  float* u     = (float*)d_ws;                               // 8.39M
  float* delta = u + (size_t)B_SZ * L_SZ * D_SZ;             // 8.39M
  float* ssm   = delta + (size_t)B_SZ * L_SZ * D_SZ;         // 0.66M
  float* chk   = ssm + (size_t)B_SZ * L_SZ * E_SZ;           // 8.39M
  float* sumdt = chk + (size_t)B_SZ * CHN * D_SZ * N_SZ;     // 0.52M
  bf16*  xwbf  = (bf16*)(sumdt + (size_t)B_SZ * CHN * D_SZ); // 0.33M bf16
  bf16*  dtwbf = xwbf + (size_t)E_SZ * D_SZ;                 // 0.26M bf16
  bf16*  dtbf  = dtwbf + (size_t)D_SZ * R_SZ;                // 0.52M bf16
  // pssm (bf16, KS*4096*160 = 10.5M bf16 = 5.25M floats) aliases chk:
  // dead after k3; chk first written by k5a. Does not reach sumdt.
  bf16*  pssm  = (bf16*)chk;
  // ubf (bf16 u for GEMM1) lives in d_out: fully rewritten every launch,
  // dead after k2; k5c overwrites d_out with the real output afterwards.
  bf16*  ubf   = (bf16*)d_out;

  hipLaunchKernelGGL(k0_cast, dim3((E_SZ * D_SZ / 4 + 255) / 256), dim3(256), 0, stream,
                     xw, xwbf, E_SZ * D_SZ / 4);
  hipLaunchKernelGGL(k0_cast, dim3((D_SZ * R_SZ / 4 + 255) / 256), dim3(256), 0, stream,
                     dtw, dtwbf, D_SZ * R_SZ / 4);
  hipLaunchKernelGGL(k1_conv, dim3(L_SZ / 64, D_SZ / 64, B_SZ), dim3(256), 0, stream,
                     h, cw, cb, u, ubf);
  hipLaunchKernelGGL(k2_gemm1, dim3(MROWS / 128, KS), dim3(256), 0, stream,
                     ubf, xwbf, pssm);
  hipLaunchKernelGGL(k3_rms, dim3(MROWS / 4), dim3(256), 0, stream,
                     pssm, ssm, dtbf, dtln, bln, cln);
  hipLaunchKernelGGL(k4_gemm2, dim3(MROWS / 64, D_SZ / 128), dim3(256), 0, stream,
                     dtbf, dtwbf, dtb, delta);
  hipLaunchKernelGGL(k5a, dim3(D_SZ / 256, CHN, B_SZ), dim3(256), 0, stream,
                     u, delta, ssm, alog, chk, sumdt);
  hipLaunchKernelGGL(k5b, dim3((B_SZ * D_SZ * N_SZ) / 256), dim3(256), 0, stream,
                     alog, sumdt, chk);
  hipLaunchKernelGGL(k5c, dim3(D_SZ / 256, CHN, B_SZ), dim3(256), 0, stream,
                     u, delta, ssm, gate, alog, dpar, chk, out);
}

// Round 7
// 274.699 us; speedup vs baseline: 5.0597x; 1.0704x over previous
//
#include <hip/hip_runtime.h>
#include <cstdint>
#include <cstddef>

#define B_SZ 2
#define D_SZ 2048
#define L_SZ 2048
#define R_SZ 128
#define N_SZ 16
#define E_SZ (R_SZ + 2*N_SZ)   // 160
#define CHN 128                // chunks over L
#define CLEN 16                // L_SZ / CHN
#define KS 16                  // split-K factor for GEMM1 (slice = 128)
#define MROWS (B_SZ * L_SZ)    // 4096

typedef __bf16 bf16;
typedef __bf16 bf16x4 __attribute__((ext_vector_type(4)));
typedef __bf16 bf16x8 __attribute__((ext_vector_type(8)));
typedef float  f32x4  __attribute__((ext_vector_type(4)));

// fast softplus: max(x,0) + log(1+exp(-|x|)) — hw v_exp_f32/v_log_f32 only.
__device__ __forceinline__ float softplus_fast(float x) {
  float e = __expf(-fabsf(x));
  return fmaxf(x, 0.f) + __logf(1.f + e);
}

// ---------------------------------------------------------------------------
// K0: fp32 -> bf16 cast (weights). n4 = n/4.
// ---------------------------------------------------------------------------
__global__ __launch_bounds__(256) void k0_cast(const float* __restrict__ src,
                                               bf16* __restrict__ dst, int n4) {
  int i = blockIdx.x * 256 + threadIdx.x;
  if (i < n4) {
    float4 v = ((const float4*)src)[i];
    bf16x4 o = { (bf16)v.x, (bf16)v.y, (bf16)v.z, (bf16)v.w };
    *(bf16x4*)&dst[4 * i] = o;
  }
}

// ---------------------------------------------------------------------------
// K1: causal depthwise conv1d (K=4) + bias + SiLU, LDS transpose.
// writes u (fp32, for scan) and ubf (bf16, for GEMM1).
// ---------------------------------------------------------------------------
__global__ __launch_bounds__(256) void k1_conv(const float* __restrict__ h,
                                               const float* __restrict__ cw,
                                               const float* __restrict__ cb,
                                               float* __restrict__ u,
                                               bf16* __restrict__ ubf) {
  __shared__ __attribute__((aligned(16))) float tile[64 * 69];
  __shared__ float wsm[64 * 4];
  __shared__ float bsm[64];
  const int b = blockIdx.z, d0 = blockIdx.y * 64, l0 = blockIdx.x * 64;
  const int tid = threadIdx.x;
  if (tid < 64) {
    bsm[tid] = cb[d0 + tid];
#pragma unroll
    for (int k = 0; k < 4; k++) wsm[tid * 4 + k] = cw[(d0 + tid) * 4 + k];
  }
  const float* hb = h + ((size_t)b * D_SZ + d0) * L_SZ;
  for (int i = tid; i < 64 * 68; i += 256) {
    int r = i / 68, c = i - r * 68;
    int gl = l0 - 3 + c;
    float v = 0.f;
    if (c < 67 && gl >= 0) v = hb[(size_t)r * L_SZ + gl];
    tile[r * 69 + c] = v;
  }
  __syncthreads();
  const size_t base = ((size_t)b * L_SZ + l0) * D_SZ + d0;
  for (int i = tid; i < 64 * 64; i += 256) {
    int ll = i >> 6, dd = i & 63;
    float s = bsm[dd];
#pragma unroll
    for (int k = 0; k < 4; k++) s = fmaf(wsm[dd * 4 + k], tile[dd * 69 + ll + k], s);
    float sv = s / (1.f + __expf(-s));
    u[base + (size_t)ll * D_SZ + dd] = sv;
    ubf[base + (size_t)ll * D_SZ + dd] = (bf16)sv;
  }
}

// ---------------------------------------------------------------------------
// K2: split-K GEMM1 via bf16 MFMA. pssm[ks][bl][e] (bf16 partials).
// Block: 128(M=bl) x 160(N=e full), K-slice 128 (BK=64 x2). grid (32, 16).
// ---------------------------------------------------------------------------
__global__ __launch_bounds__(256) void k2_gemm1(const bf16* __restrict__ ubf,
                                                const bf16* __restrict__ xwbf,
                                                bf16* __restrict__ pssm) {
  __shared__ __attribute__((aligned(16))) bf16 aS[128 * 72];
  __shared__ __attribute__((aligned(16))) bf16 bS[160 * 72];
  const int bl0 = blockIdx.x * 128;
  const int kbase = blockIdx.y * (D_SZ / KS);   // slice = 128
  const int tid = threadIdx.x;
  const int wv = tid >> 6, lane = tid & 63;
  const int ml = lane & 15, quad = lane >> 4;
  f32x4 acc[2][10] = {};
  for (int k0 = kbase; k0 < kbase + D_SZ / KS; k0 += 64) {
    for (int i = tid; i < 1024; i += 256) {          // A: 128x64 bf16
      int r = i >> 3, c = (i & 7) * 8;
      *(uint4*)&aS[r * 72 + c] = *(const uint4*)&ubf[(size_t)(bl0 + r) * D_SZ + k0 + c];
    }
    for (int i = tid; i < 1280; i += 256) {          // B: 160x64 bf16
      int r = i >> 3, c = (i & 7) * 8;
      *(uint4*)&bS[r * 72 + c] = *(const uint4*)&xwbf[(size_t)r * D_SZ + k0 + c];
    }
    __syncthreads();
#pragma unroll
    for (int ks = 0; ks < 2; ++ks) {
      bf16x8 af0 = *(const bf16x8*)&aS[(wv * 32 + ml) * 72 + ks * 32 + quad * 8];
      bf16x8 af1 = *(const bf16x8*)&aS[(wv * 32 + 16 + ml) * 72 + ks * 32 + quad * 8];
#pragma unroll
      for (int j = 0; j < 10; ++j) {
        bf16x8 bfv = *(const bf16x8*)&bS[(j * 16 + ml) * 72 + ks * 32 + quad * 8];
        acc[0][j] = __builtin_amdgcn_mfma_f32_16x16x32_bf16(af0, bfv, acc[0][j], 0, 0, 0);
        acc[1][j] = __builtin_amdgcn_mfma_f32_16x16x32_bf16(af1, bfv, acc[1][j], 0, 0, 0);
      }
    }
    __syncthreads();
  }
  bf16* pb = pssm + (size_t)blockIdx.y * MROWS * E_SZ;
#pragma unroll
  for (int mi = 0; mi < 2; ++mi)
#pragma unroll
    for (int j = 0; j < 10; ++j)
#pragma unroll
      for (int r = 0; r < 4; ++r) {
        int row = bl0 + wv * 32 + mi * 16 + quad * 4 + r;   // C/D: row=quad*4+reg
        pb[(size_t)row * E_SZ + j * 16 + ml] = (bf16)acc[mi][j][r];  // col=lane&15
      }
}

// ---------------------------------------------------------------------------
// K3: reduce KS bf16 partials + RMSNorm. dt -> dtbf (bf16 [4096][128]);
// B/C -> ssm fp32 (offsets 128..160 of each row). one wave per row.
// ---------------------------------------------------------------------------
__global__ __launch_bounds__(256) void k3_rms(const bf16* __restrict__ pssm,
                                              float* __restrict__ ssm,
                                              bf16* __restrict__ dtbf,
                                              const float* __restrict__ dtln,
                                              const float* __restrict__ bln,
                                              const float* __restrict__ cln) {
  const int lane = threadIdx.x & 63;
  const int wv = threadIdx.x >> 6;
  const size_t row = (size_t)blockIdx.x * 4 + wv;
  float v0 = 0.f, v1 = 0.f, v2 = 0.f;
#pragma unroll
  for (int ks = 0; ks < KS; ++ks) {
    const bf16* q = pssm + ((size_t)ks * MROWS + row) * E_SZ;
    v0 += (float)q[lane];
    v1 += (float)q[64 + lane];
    if (lane < 32) v2 += (float)q[128 + lane];
  }
  float sdt = v0 * v0 + v1 * v1;
#pragma unroll
  for (int m = 1; m < 64; m <<= 1) sdt += __shfl_xor(sdt, m);
  float sv2 = v2 * v2;
#pragma unroll
  for (int m = 1; m < 16; m <<= 1) sv2 += __shfl_xor(sv2, m);
  float sB = __shfl(sv2, 0);
  float sC = __shfl(sv2, 16);
  float rdt = rsqrtf(sdt * (1.f / 128.f) + 1e-6f);
  float rB  = rsqrtf(sB  * (1.f / 16.f)  + 1e-6f);
  float rC  = rsqrtf(sC  * (1.f / 16.f)  + 1e-6f);
  dtbf[row * R_SZ + lane]      = (bf16)(v0 * rdt * dtln[lane]);
  dtbf[row * R_SZ + 64 + lane] = (bf16)(v1 * rdt * dtln[64 + lane]);
  float* p = ssm + row * E_SZ;
  if (lane < 16)      p[128 + lane] = v2 * rB * bln[lane];
  else if (lane < 32) p[128 + lane] = v2 * rC * cln[lane - 16];
}

// ---------------------------------------------------------------------------
// K4: delta = softplus(dt @ dt_w^T + dt_b) via bf16 MFMA.
// M=4096, N=2048, K=128. Block 64x128, BK=64 x2, wave tile 32x64.
// Epilogue: softplus_fast (hw exp/log) — log1pf was ~200 VALU inst/output (R6).
// ---------------------------------------------------------------------------
__global__ __launch_bounds__(256) void k4_gemm2(const bf16* __restrict__ dtbf,
                                                const bf16* __restrict__ dtwbf,
                                                const float* __restrict__ dtb,
                                                float* __restrict__ delta) {
  __shared__ __attribute__((aligned(16))) bf16 aS[64 * 72];
  __shared__ __attribute__((aligned(16))) bf16 bS[128 * 72];
  const int bl0 = blockIdx.x * 64, d0 = blockIdx.y * 128;
  const int tid = threadIdx.x;
  const int wv = tid >> 6, lane = tid & 63;
  const int ml = lane & 15, quad = lane >> 4;
  const int wm = (wv >> 1) * 32, wn = (wv & 1) * 64;
  f32x4 acc[2][4] = {};
  for (int k0 = 0; k0 < R_SZ; k0 += 64) {
    for (int i = tid; i < 512; i += 256) {           // A: 64x64 bf16
      int r = i >> 3, c = (i & 7) * 8;
      *(uint4*)&aS[r * 72 + c] = *(const uint4*)&dtbf[(size_t)(bl0 + r) * R_SZ + k0 + c];
    }
    for (int i = tid; i < 1024; i += 256) {          // B: 128x64 bf16
      int r = i >> 3, c = (i & 7) * 8;
      *(uint4*)&bS[r * 72 + c] = *(const uint4*)&dtwbf[(size_t)(d0 + r) * R_SZ + k0 + c];
    }
    __syncthreads();
#pragma unroll
    for (int ks = 0; ks < 2; ++ks) {
      bf16x8 af[2], bfv[4];
#pragma unroll
      for (int mi = 0; mi < 2; ++mi)
        af[mi] = *(const bf16x8*)&aS[(wm + mi * 16 + ml) * 72 + ks * 32 + quad * 8];
#pragma unroll
      for (int nj = 0; nj < 4; ++nj)
        bfv[nj] = *(const bf16x8*)&bS[(wn + nj * 16 + ml) * 72 + ks * 32 + quad * 8];
#pragma unroll
      for (int mi = 0; mi < 2; ++mi)
#pragma unroll
        for (int nj = 0; nj < 4; ++nj)
          acc[mi][nj] = __builtin_amdgcn_mfma_f32_16x16x32_bf16(af[mi], bfv[nj], acc[mi][nj], 0, 0, 0);
    }
    __syncthreads();
  }
#pragma unroll
  for (int nj = 0; nj < 4; ++nj) {
    const int d = d0 + wn + nj * 16 + ml;
    const float bias = dtb[d];
#pragma unroll
    for (int mi = 0; mi < 2; ++mi)
#pragma unroll
      for (int r = 0; r < 4; ++r) {
        int row = bl0 + wm + mi * 16 + quad * 4 + r;
        delta[(size_t)row * D_SZ + d] = softplus_fast(acc[mi][nj][r] + bias);
      }
  }
}

// ---------------------------------------------------------------------------
// K5a: chunked scan, phase A. thread = (b, d, chunk), N=16 states in regs.
// ---------------------------------------------------------------------------
__global__ __launch_bounds__(256) void k5a(const float* __restrict__ u,
                                           const float* __restrict__ delta,
                                           const float* __restrict__ ssm,
                                           const float* __restrict__ alog,
                                           float* __restrict__ chk,
                                           float* __restrict__ sumdt) {
  __shared__ __attribute__((aligned(16))) float Bs[CLEN * N_SZ];  // 1 KB
  const int tid = threadIdx.x;
  const int d = blockIdx.x * 256 + tid;
  const int c = blockIdx.y, b = blockIdx.z;
  const size_t l0 = (size_t)c * CLEN;
  const float* bp = ssm + ((size_t)b * L_SZ + l0) * E_SZ + R_SZ;
  if (tid < CLEN * N_SZ) {
    int t = tid >> 4, n = tid & 15;
    Bs[tid] = bp[(size_t)t * E_SZ + n];
  }
  float a[N_SZ], s[N_SZ];
#pragma unroll
  for (int i = 0; i < 4; i++) {
    float4 al = *(const float4*)&alog[(size_t)d * N_SZ + 4 * i];
    a[4 * i + 0] = -__expf(al.x); a[4 * i + 1] = -__expf(al.y);
    a[4 * i + 2] = -__expf(al.z); a[4 * i + 3] = -__expf(al.w);
  }
#pragma unroll
  for (int n = 0; n < N_SZ; n++) s[n] = 0.f;
  const float* dp = delta + ((size_t)b * L_SZ + l0) * D_SZ + d;
  const float* up = u     + ((size_t)b * L_SZ + l0) * D_SZ + d;
  __syncthreads();
  float sdt = 0.f;
  float dt = dp[0], ut = up[0];
#pragma unroll 4
  for (int t = 0; t < CLEN; ++t) {
    const int tn = (t + 1 < CLEN) ? t + 1 : t;
    float dt_n = dp[(size_t)tn * D_SZ];
    float ut_n = up[(size_t)tn * D_SZ];
    float du = dt * ut;
    sdt += dt;
#pragma unroll
    for (int n = 0; n < N_SZ; n++)
      s[n] = fmaf(__expf(a[n] * dt), s[n], du * Bs[t * N_SZ + n]);
    dt = dt_n; ut = ut_n;
  }
  float* cp = chk + (((size_t)b * CHN + c) * D_SZ + d) * N_SZ;
#pragma unroll
  for (int i = 0; i < 4; i++)
    *(float4*)&cp[4 * i] = make_float4(s[4 * i], s[4 * i + 1], s[4 * i + 2], s[4 * i + 3]);
  sumdt[((size_t)b * CHN + c) * D_SZ + d] = sdt;
}

// ---------------------------------------------------------------------------
// K5b: prefix over chunk summaries, in place. thread = (b, d, n).
// ---------------------------------------------------------------------------
__global__ __launch_bounds__(256) void k5b(const float* __restrict__ alog,
                                           const float* __restrict__ sumdt,
                                           float* __restrict__ chk) {
  const int g = blockIdx.x * 256 + threadIdx.x;      // over B*D*16 = 65536
  const int n = g & 15;
  const int d = (g >> 4) & (D_SZ - 1);
  const int b = g >> 15;
  const float a = -__expf(alog[(size_t)d * N_SZ + n]);
  float s = 0.f;
  float v  = chk[(((size_t)b * CHN) * D_SZ + d) * N_SZ + n];
  float sd = sumdt[((size_t)b * CHN) * D_SZ + d];
  for (int c = 0; c < CHN; ++c) {
    const int cn = (c + 1 < CHN) ? c + 1 : c;
    float v_n  = chk[(((size_t)b * CHN + cn) * D_SZ + d) * N_SZ + n];
    float sd_n = sumdt[((size_t)b * CHN + cn) * D_SZ + d];
    float init = s;
    s = fmaf(__expf(a * sd), s, v);
    chk[(((size_t)b * CHN + c) * D_SZ + d) * N_SZ + n] = init;
    v = v_n; sd = sd_n;
  }
}

// ---------------------------------------------------------------------------
// K5c: chunked scan, phase C. Re-run chunk from init state; fused y, skip, gate.
// ---------------------------------------------------------------------------
__global__ __launch_bounds__(256) void k5c(const float* __restrict__ u,
                                           const float* __restrict__ delta,
                                           const float* __restrict__ ssm,
                                           const float* __restrict__ gate,
                                           const float* __restrict__ alog,
                                           const float* __restrict__ dparam,
                                           const float* __restrict__ chk,
                                           float* __restrict__ out) {
  __shared__ __attribute__((aligned(16))) float Bs[CLEN * N_SZ];
  __shared__ __attribute__((aligned(16))) float Cs[CLEN * N_SZ];
  const int tid = threadIdx.x;
  const int d = blockIdx.x * 256 + tid;
  const int c = blockIdx.y, b = blockIdx.z;
  const size_t l0 = (size_t)c * CLEN;
  const float* bp = ssm + ((size_t)b * L_SZ + l0) * E_SZ + R_SZ;
  if (tid < CLEN * N_SZ) {
    int t = tid >> 4, n = tid & 15;
    Bs[tid] = bp[(size_t)t * E_SZ + n];
    Cs[tid] = bp[(size_t)t * E_SZ + N_SZ + n];
  }
  float a[N_SZ], s[N_SZ];
#pragma unroll
  for (int i = 0; i < 4; i++) {
    float4 al = *(const float4*)&alog[(size_t)d * N_SZ + 4 * i];
    a[4 * i + 0] = -__expf(al.x); a[4 * i + 1] = -__expf(al.y);
    a[4 * i + 2] = -__expf(al.z); a[4 * i + 3] = -__expf(al.w);
  }
  const float* cp = chk + (((size_t)b * CHN + c) * D_SZ + d) * N_SZ;
#pragma unroll
  for (int i = 0; i < 4; i++) {
    float4 sv = *(const float4*)&cp[4 * i];
    s[4 * i] = sv.x; s[4 * i + 1] = sv.y; s[4 * i + 2] = sv.z; s[4 * i + 3] = sv.w;
  }
  const float dpv = dparam[d];
  const float* dp = delta + ((size_t)b * L_SZ + l0) * D_SZ + d;
  const float* up = u     + ((size_t)b * L_SZ + l0) * D_SZ + d;
  const float* gp = gate  + ((size_t)b * D_SZ + d) * L_SZ + l0;
  float* op = out + ((size_t)b * L_SZ + l0) * D_SZ + d;
  __syncthreads();
  float dt = dp[0], ut = up[0], gv = gp[0];
#pragma unroll 4
  for (int t = 0; t < CLEN; ++t) {
    const int tn = (t + 1 < CLEN) ? t + 1 : t;
    float dt_n = dp[(size_t)tn * D_SZ];
    float ut_n = up[(size_t)tn * D_SZ];
    float gv_n = gp[tn];
    float du = dt * ut;
    float y = 0.f;
#pragma unroll
    for (int n = 0; n < N_SZ; n++) {
      s[n] = fmaf(__expf(a[n] * dt), s[n], du * Bs[t * N_SZ + n]);
      y = fmaf(s[n], Cs[t * N_SZ + n], y);
    }
    float sg = gv / (1.f + __expf(-gv));
    op[(size_t)t * D_SZ] = fmaf(ut, dpv, y) * sg;
    dt = dt_n; ut = ut_n; gv = gv_n;
  }
}

// ---------------------------------------------------------------------------
extern "C" void kernel_launch(void* const* d_in, const int* in_sizes, int n_in,
                              void* d_out, int out_size, void* d_ws, size_t ws_size,
                              hipStream_t stream) {
  const float* h    = (const float*)d_in[0];
  const float* gate = (const float*)d_in[1];
  const float* cw   = (const float*)d_in[2];
  const float* cb   = (const float*)d_in[3];
  const float* xw   = (const float*)d_in[4];
  const float* dtw  = (const float*)d_in[5];
  const float* dtb  = (const float*)d_in[6];
  const float* alog = (const float*)d_in[7];
  const float* dpar = (const float*)d_in[8];
  const float* dtln = (const float*)d_in[9];
  const float* bln  = (const float*)d_in[10];
  const float* cln  = (const float*)d_in[11];
  float* out = (float*)d_out;

  float* u     = (float*)d_ws;                               // 8.39M floats
  float* delta = u + (size_t)B_SZ * L_SZ * D_SZ;             // 8.39M
  float* ssm   = delta + (size_t)B_SZ * L_SZ * D_SZ;         // 0.66M
  float* chk   = ssm + (size_t)B_SZ * L_SZ * E_SZ;           // 8.39M
  float* sumdt = chk + (size_t)B_SZ * CHN * D_SZ * N_SZ;     // 0.52M
  bf16*  xwbf  = (bf16*)(sumdt + (size_t)B_SZ * CHN * D_SZ); // 0.33M bf16
  bf16*  dtwbf = xwbf + (size_t)E_SZ * D_SZ;                 // 0.26M bf16
  bf16*  dtbf  = dtwbf + (size_t)D_SZ * R_SZ;                // 0.52M bf16
  bf16*  pssm  = (bf16*)chk;   // aliases chk: dead after k3; chk written by k5a
  bf16*  ubf   = (bf16*)d_out; // staging in d_out: dead after k2; k5c rewrites

  hipLaunchKernelGGL(k0_cast, dim3((E_SZ * D_SZ / 4 + 255) / 256), dim3(256), 0, stream,
                     xw, xwbf, E_SZ * D_SZ / 4);
  hipLaunchKernelGGL(k0_cast, dim3((D_SZ * R_SZ / 4 + 255) / 256), dim3(256), 0, stream,
                     dtw, dtwbf, D_SZ * R_SZ / 4);
  hipLaunchKernelGGL(k1_conv, dim3(L_SZ / 64, D_SZ / 64, B_SZ), dim3(256), 0, stream,
                     h, cw, cb, u, ubf);
  hipLaunchKernelGGL(k2_gemm1, dim3(MROWS / 128, KS), dim3(256), 0, stream,
                     ubf, xwbf, pssm);
  hipLaunchKernelGGL(k3_rms, dim3(MROWS / 4), dim3(256), 0, stream,
                     pssm, ssm, dtbf, dtln, bln, cln);
  hipLaunchKernelGGL(k4_gemm2, dim3(MROWS / 64, D_SZ / 128), dim3(256), 0, stream,
                     dtbf, dtwbf, dtb, delta);
  hipLaunchKernelGGL(k5a, dim3(D_SZ / 256, CHN, B_SZ), dim3(256), 0, stream,
                     u, delta, ssm, alog, chk, sumdt);
  hipLaunchKernelGGL(k5b, dim3((B_SZ * D_SZ * N_SZ) / 256), dim3(256), 0, stream,
                     alog, sumdt, chk);
  hipLaunchKernelGGL(k5c, dim3(D_SZ / 256, CHN, B_SZ), dim3(256), 0, stream,
                     u, delta, ssm, gate, alog, dpar, chk, out);
}